// Round 14
// baseline (505.720 us; speedup 1.0000x reference)
//
#include <hip/hip_runtime.h>
#include <hip/hip_bf16.h>

namespace {

constexpr int NB = 8;
constexpr int NV = 20000;
constexpr int NC = 256;
constexpr int NK = 128;
constexpr float LMBDA = 100.0f;
constexpr int KSTEP = 32;
constexpr int CHUNKS = 16;      // v-chunks; chunk 0 gets 40 steps, rest 39

typedef __attribute__((ext_vector_type(8))) short bf16x8;
typedef __attribute__((ext_vector_type(4))) float f32x4;

// HW packed conversion: low16 = bf16(a), high16 = bf16(c); RTNE.
__device__ __forceinline__ uint cvtpk(float a, float c) {
  uint r;
  asm("v_cvt_pk_bf16_f32 %0, %1, %2" : "=v"(r) : "v"(a), "v"(c));
  return r;
}

// ---------------------------------------------------------------------------
// 1) Spectral projection via split-bf16 MFMA (hi*hi + hi*lo + lo*hi).
//    A-operands loaded DIRECTLY from global E into registers (cvt at load):
//    MFMA A-frag layout lane l -> row l&15, v-slots (l>>4)*8..+7, so lane
//    (lrow,lcol) reads E[row=wm*64+fi*16+lcol][v0+s*32+lrow*8..+7].
//    Only B goes through LDS (16 KB/buf, double-buffered). Removes half the
//    LDS traffic and the E-stage; bit-identical math (same cvt pairs, same
//    MFMA order).
// ---------------------------------------------------------------------------
template <int MODE>
__global__ __launch_bounds__(256, 2) void proj_mfma(
    const float* __restrict__ Ex, const float* __restrict__ Fx,
    const float* __restrict__ Ey, const float* __restrict__ Fy,
    float* __restrict__ A, float* __restrict__ Bm, float* __restrict__ P)
{
  extern __shared__ ushort smem[];         // 2 bufs x BH 8192 ushorts (16 KB)

  const int chunk = blockIdx.x;            // 0..15
  const int ct    = blockIdx.y;            // 0..1 (c half)
  const int bs    = blockIdx.z;            // b*2+side
  const int b     = bs >> 1;
  const int side  = bs & 1;
  const float* __restrict__ E = (side ? Ey : Ex) + (size_t)b * NK * NV;
  const float* __restrict__ F = (side ? Fy : Fx) + (size_t)b * NV * NC;
  float* __restrict__ Out = (side ? Bm : A) + (size_t)b * NK * NC;
  const int cb = ct * 128;

  const int start = chunk * 39 + (chunk > 0 ? 1 : 0);
  const int nsteps = 39 + (chunk == 0 ? 1 : 0);
  const int v0 = start * KSTEP;

  const int tid  = threadIdx.x;            // 0..255
  const int lane = tid & 63;
  const int w    = tid >> 6;               // 0..3
  const int wm   = w >> 1;                 // 0..1 (64-row group)
  const int wn   = w & 1;                  // 0..1 (64-col group)
  const int lrow = lane >> 4;              // 0..3
  const int lcol = lane & 15;

  // A direct-load base: row = wm*64 + fi*16 + lcol, v = v0 + lrow*8
  const float* Abase = E + (size_t)(wm * 64 + lcol) * NV + v0 + lrow * 8;

  // B staging: thread -> vgroup bg = tid>>6, col pair c0, c0+1
  const int bg  = tid >> 6;                // 0..3
  const int c0  = (tid & 63) * 2;          // 0..126 (even)
  const int c1  = c0 + 1;
  const float* Fbase = F + (size_t)(v0 + bg * 8) * NC + cb + c0;

  f32x4 acc[4][4];
#pragma unroll
  for (int fi = 0; fi < 4; fi++)
#pragma unroll
    for (int ni = 0; ni < 4; ni++) acc[fi][ni] = (f32x4)0.f;

  auto loadF = [&](int t, float2* f) {
    const float* p = Fbase + (size_t)t * KSTEP * NC;
#pragma unroll
    for (int j = 0; j < 8; j++) f[j] = *(const float2*)(p + (size_t)j * NC);
  };

  // Load + convert one step's A-fragments into registers (hi/lo bf16x8 as uint4).
  auto loadcvtA = [&](int t, uint4 (&ah)[4], uint4 (&al)[4]) {
#pragma unroll
    for (int fi = 0; fi < 4; fi++) {
      const float* p = Abase + (size_t)fi * 16 * NV + (size_t)t * KSTEP;
      const float4 a0 = *(const float4*)(p);
      const float4 a1 = *(const float4*)(p + 4);
      const uint h0 = cvtpk(a0.x, a0.y), h1 = cvtpk(a0.z, a0.w);
      const uint h2 = cvtpk(a1.x, a1.y), h3 = cvtpk(a1.z, a1.w);
      const uint l0 = cvtpk(a0.x - __uint_as_float(h0 << 16),
                            a0.y - __uint_as_float(h0 & 0xffff0000u));
      const uint l1 = cvtpk(a0.z - __uint_as_float(h1 << 16),
                            a0.w - __uint_as_float(h1 & 0xffff0000u));
      const uint l2 = cvtpk(a1.x - __uint_as_float(h2 << 16),
                            a1.y - __uint_as_float(h2 & 0xffff0000u));
      const uint l3 = cvtpk(a1.z - __uint_as_float(h3 << 16),
                            a1.w - __uint_as_float(h3 & 0xffff0000u));
      ah[fi] = make_uint4(h0, h1, h2, h3);
      al[fi] = make_uint4(l0, l1, l2, l3);
    }
  };

  auto stageB = [&](int buf, const float2* f) {
    ushort* BHb = smem + buf * 8192;
    const int frag = c0 >> 4;                    // c1 same frag (c0 even)
    const int ent0 = (((c0 & 15) + frag) & 15) + bg * 16;
    const int ent1 = (((c1 & 15) + frag) & 15) + bg * 16;
    uint h0[4], l0[4], h1[4], l1[4];
#pragma unroll
    for (int i = 0; i < 4; i++) {
      const float a0 = f[2 * i].x, b0 = f[2 * i + 1].x;
      const float a1 = f[2 * i].y, b1 = f[2 * i + 1].y;
      uint h = cvtpk(a0, b0);
      h0[i] = h;
      l0[i] = cvtpk(a0 - __uint_as_float(h << 16),
                    b0 - __uint_as_float(h & 0xffff0000u));
      h = cvtpk(a1, b1);
      h1[i] = h;
      l1[i] = cvtpk(a1 - __uint_as_float(h << 16),
                    b1 - __uint_as_float(h & 0xffff0000u));
    }
    *(uint4*)(BHb + frag * 512 + ent0 * 8)        = make_uint4(h0[0], h0[1], h0[2], h0[3]);
    *(uint4*)(BHb + 4096 + frag * 512 + ent0 * 8) = make_uint4(l0[0], l0[1], l0[2], l0[3]);
    *(uint4*)(BHb + frag * 512 + ent1 * 8)        = make_uint4(h1[0], h1[1], h1[2], h1[3]);
    *(uint4*)(BHb + 4096 + frag * 512 + ent1 * 8) = make_uint4(l1[0], l1[1], l1[2], l1[3]);
  };

  auto domfma = [&](int buf, const uint4 (&ah)[4], const uint4 (&al)[4]) {
    const ushort* BHb = smem + buf * 8192;
    bf16x8 bHf[4], bLf[4];
#pragma unroll
    for (int ni = 0; ni < 4; ni++) {
      int cg = wn * 4 + ni;
      int entB = ((lcol + cg) & 15) + lrow * 16;
      bHf[ni] = *(const bf16x8*)(BHb + cg * 512 + entB * 8);
      bLf[ni] = *(const bf16x8*)(BHb + 4096 + cg * 512 + entB * 8);
    }
#pragma unroll
    for (int fi = 0; fi < 4; fi++) {
      bf16x8 aH = *(const bf16x8*)&ah[fi];
      bf16x8 aL = *(const bf16x8*)&al[fi];
#pragma unroll
      for (int ni = 0; ni < 4; ni++) {
        acc[fi][ni] = __builtin_amdgcn_mfma_f32_16x16x32_bf16(aH, bHf[ni], acc[fi][ni], 0, 0, 0);
        acc[fi][ni] = __builtin_amdgcn_mfma_f32_16x16x32_bf16(aH, bLf[ni], acc[fi][ni], 0, 0, 0);
        acc[fi][ni] = __builtin_amdgcn_mfma_f32_16x16x32_bf16(aL, bHf[ni], acc[fi][ni], 0, 0, 0);
      }
    }
  };

  // ---- pipeline prologue ----
  uint4 ahA[4], alA[4], ahB[4], alB[4];
  float2 fA[8], fB[8];
  loadF(0, fA);
  loadcvtA(0, ahA, alA);
  stageB(0, fA);
  {
    const int t1 = (1 < nsteps) ? 1 : 0;
    loadF(t1, fB);
    loadcvtA(t1, ahB, alB);
  }
  __syncthreads();

  // ---- main loop: ONE barrier per step; static reg-set names per parity ----
  for (int s = 0; s < nsteps; s++) {
    const int bufc = s & 1;
    if ((s & 1) == 0) {
      if (s + 1 < nsteps) stageB(bufc ^ 1, fB);
      if (s + 2 < nsteps) loadF(s + 2, fA);
      domfma(bufc, ahA, alA);
      if (s + 2 < nsteps) loadcvtA(s + 2, ahA, alA);
    } else {
      if (s + 1 < nsteps) stageB(bufc ^ 1, fA);
      if (s + 2 < nsteps) loadF(s + 2, fB);
      domfma(bufc, ahB, alB);
      if (s + 2 < nsteps) loadcvtA(s + 2, ahB, alB);
    }
    __syncthreads();
  }

  // ---- epilogue: C/D layout col=lane&15, row=(lane>>4)*4+reg ----
#pragma unroll
  for (int fi = 0; fi < 4; fi++) {
#pragma unroll
    for (int ni = 0; ni < 4; ni++) {
      const float* av = (const float*)&acc[fi][ni];
#pragma unroll
      for (int q = 0; q < 4; q++) {
        int row = wm * 64 + fi * 16 + lrow * 4 + q;
        int col = cb + wn * 64 + ni * 16 + lcol;
        if (MODE == 0) {
          P[(((size_t)chunk * 16 + bs) * NK + row) * NC + col] = av[q];
        } else {
          atomicAdd(&Out[(size_t)row * NC + col], av[q]);
        }
      }
    }
  }
}

__global__ __launch_bounds__(256) void reduce_kernel(
    const float* __restrict__ P, float* __restrict__ AB)
{
  const int g = blockIdx.x * 256 + threadIdx.x;
  const int bsi = g >> 13;
  const int rem4 = g & 8191;
  const int side = bsi & 1, b = bsi >> 1;
  float4 s = make_float4(0.f, 0.f, 0.f, 0.f);
#pragma unroll
  for (int ch = 0; ch < CHUNKS; ch++) {
    float4 v = *(const float4*)(P + (((size_t)ch * 16 + bsi) * 8192 + rem4) * 4);
    s.x += v.x; s.y += v.y; s.z += v.z; s.w += v.w;
  }
  *(float4*)(AB + ((size_t)side * 262144 + (size_t)b * 8192 * 4 + (size_t)rem4 * 4)) = s;
}

// ---------------------------------------------------------------------------
// 2) Gram
// ---------------------------------------------------------------------------
__global__ __launch_bounds__(256) void gram_kernel(
    const float* __restrict__ A, const float* __restrict__ Bm,
    float* __restrict__ AAt, float* __restrict__ BAt)
{
  const int i0 = blockIdx.x * 8;
  const int b  = blockIdx.y;
  __shared__ float Xi[16][260];
  const float* __restrict__ Ab = A  + (size_t)b * NK * NC;
  const float* __restrict__ Bb = Bm + (size_t)b * NK * NC;
  const int tid = threadIdx.x;
  for (int idx = tid; idx < 16 * 64; idx += 256) {
    int row = idx >> 6, c4 = idx & 63;
    const float* src = (row < 8) ? (Ab + (size_t)(i0 + row) * NC)
                                 : (Bb + (size_t)(i0 + row - 8) * NC);
    *(float4*)&Xi[row][c4 * 4] = *(const float4*)(src + c4 * 4);
  }
  __syncthreads();
  const int j = tid & 127;
  const int m = tid >> 7;
  const float* __restrict__ Arow = Ab + (size_t)j * NC;
  float accv[8];
#pragma unroll
  for (int i = 0; i < 8; i++) accv[i] = 0.f;
  for (int c4 = 0; c4 < 64; c4++) {
    float4 a4 = *(const float4*)(Arow + c4 * 4);
#pragma unroll
    for (int i = 0; i < 8; i++) {
      float4 x4 = *(const float4*)&Xi[m * 8 + i][c4 * 4];
      accv[i] = fmaf(x4.x, a4.x, accv[i]);
      accv[i] = fmaf(x4.y, a4.y, accv[i]);
      accv[i] = fmaf(x4.z, a4.z, accv[i]);
      accv[i] = fmaf(x4.w, a4.w, accv[i]);
    }
  }
  float* Outp = (m ? BAt : AAt) + ((size_t)b * NK + i0) * NK + j;
#pragma unroll
  for (int i = 0; i < 8; i++) Outp[(size_t)i * NK] = accv[i];
}

// ---------------------------------------------------------------------------
// 3) Mask D
// ---------------------------------------------------------------------------
__global__ __launch_bounds__(256) void mask_kernel(
    const float* __restrict__ evx, const float* __restrict__ evy,
    float* __restrict__ Dm)
{
  const int b = blockIdx.x;
  const int tid = threadIdx.x;
  __shared__ float red[256];
  __shared__ float t1x[128], t2x[128], t1y[128], t2y[128];
  float v = (tid < 128) ? evx[b * 128 + tid] : evy[b * 128 + (tid - 128)];
  red[tid] = v;
  __syncthreads();
  for (int sft = 128; sft > 0; sft >>= 1) {
    if (tid < sft) red[tid] = fmaxf(red[tid], red[tid + sft]);
    __syncthreads();
  }
  const float inv_scale = 1.0f / red[0];
  if (tid < 128) {
    float e = evx[b * 128 + tid] * inv_scale;
    float g = sqrtf(e);
    float d = 1.f / (g * g + 1.f);
    t1x[tid] = g * d;  t2x[tid] = d;
  } else {
    int i = tid - 128;
    float e = evy[b * 128 + i] * inv_scale;
    float g = sqrtf(e);
    float d = 1.f / (g * g + 1.f);
    t1y[i] = g * d;  t2y[i] = d;
  }
  __syncthreads();
  float* __restrict__ Db = Dm + (size_t)b * NK * NK;
  for (int idx = tid; idx < NK * NK; idx += 256) {
    int i = idx >> 7, jj = idx & 127;
    float re = t1y[i] - t1x[jj];
    float im = t2y[i] - t2x[jj];
    Db[idx] = re * re + im * im;
  }
}

// ---------------------------------------------------------------------------
// 4) Blocked Gauss-Jordan inversion, W=8 panels (unchanged, verified).
// ---------------------------------------------------------------------------
__global__ __launch_bounds__(512) void invert_kernel(
    const float* __restrict__ AAt, float* __restrict__ Sinv)
{
  extern __shared__ float sh[];
  float* M = sh;                       // [128][132]
  float* R = sh + 128 * 132;           // [8][132] pivot-row snapshot
  const int b = blockIdx.x;
  const int tid = threadIdx.x;
  const float* __restrict__ Sb = AAt + (size_t)b * NK * NK;
  for (int idx = tid; idx < NK * NK; idx += 512) {
    M[(idx >> 7) * 132 + (idx & 127)] = Sb[idx];
  }
  __syncthreads();
  const int r = tid & 127;
  const int h = tid >> 7;
  const int c0 = h * 32;

  for (int p = 0; p < 16; p++) {
    const int J0 = p * 8;
    const bool inJ = (r >= J0) && (r < J0 + 8);
    const int i0 = r - J0;

    float g[8][8];
#pragma unroll
    for (int i = 0; i < 8; i++)
#pragma unroll
      for (int j = 0; j < 8; j++) g[i][j] = M[(J0 + i) * 132 + J0 + j];

#pragma unroll
    for (int j = 0; j < 8; j++) {
      const float invd = 1.f / g[j][j];
#pragma unroll
      for (int i = 0; i < 8; i++) {
        if (i == j) continue;
        const float f = g[i][j] * invd;
#pragma unroll
        for (int c = 0; c < 8; c++) {
          if (c == j) continue;
          g[i][c] = fmaf(-f, g[j][c], g[i][c]);
        }
        g[i][j] = -f;
      }
#pragma unroll
      for (int c = 0; c < 8; c++) {
        if (c == j) continue;
        g[j][c] *= invd;
      }
      g[j][j] = invd;
    }

    float c8[8];
    if (inJ) {
#pragma unroll
      for (int q = 0; q < 8; q++) {
        float v = 0.f;
#pragma unroll
        for (int i = 0; i < 8; i++)
          if (i0 == i) v = g[i][q];
        c8[q] = ((i0 == q) ? 1.f : 0.f) - v;
      }
    } else {
      float mr8[8];
#pragma unroll
      for (int k = 0; k < 8; k++) mr8[k] = M[r * 132 + J0 + k];
#pragma unroll
      for (int q = 0; q < 8; q++) {
        float a = 0.f;
#pragma unroll
        for (int k = 0; k < 8; k++) a = fmaf(mr8[k], g[k][q], a);
        c8[q] = a;
      }
    }

    if (inJ) {
#pragma unroll
      for (int i = 0; i < 8; i++)
        *(float4*)&R[i0 * 132 + c0 + i * 4] = *(const float4*)&M[r * 132 + c0 + i * 4];
    }
    __syncthreads();

    float4 m[8];
#pragma unroll
    for (int i = 0; i < 8; i++) m[i] = *(const float4*)&M[r * 132 + c0 + i * 4];
#pragma unroll
    for (int k = 0; k < 8; k++) {
      const float f = c8[k];
#pragma unroll
      for (int i = 0; i < 8; i++) {
        float4 rv = *(const float4*)&R[k * 132 + c0 + i * 4];
        m[i].x = fmaf(-f, rv.x, m[i].x);
        m[i].y = fmaf(-f, rv.y, m[i].y);
        m[i].z = fmaf(-f, rv.z, m[i].z);
        m[i].w = fmaf(-f, rv.w, m[i].w);
      }
    }
    {
      const bool panelH = (h == (J0 >> 5));
      const int q4 = (J0 & 31) >> 2;
      float sp[8];
#pragma unroll
      for (int q = 0; q < 8; q++)
        sp[q] = -c8[q] + ((inJ && i0 == q) ? 1.f : 0.f);
      const float4 lo = make_float4(sp[0], sp[1], sp[2], sp[3]);
      const float4 hi = make_float4(sp[4], sp[5], sp[6], sp[7]);
#pragma unroll
      for (int i = 0; i < 8; i++) {
        if (panelH && i == q4)     m[i] = lo;
        if (panelH && i == q4 + 1) m[i] = hi;
      }
    }
#pragma unroll
    for (int i = 0; i < 8; i++) *(float4*)&M[r * 132 + c0 + i * 4] = m[i];
    __syncthreads();
  }

  float* __restrict__ Ob = Sinv + (size_t)b * NK * NK;
  for (int idx = tid; idx < NK * NK; idx += 512) {
    Ob[idx] = M[(idx >> 7) * 132 + (idx & 127)];
  }
}

// ---------------------------------------------------------------------------
// 4b) Newton-Schulz, COLUMN-PARALLEL (load-bearing; round-9/10 A/B).
// ---------------------------------------------------------------------------
__global__ __launch_bounds__(256) void ns_kernel(
    const float* __restrict__ AAt, const float* __restrict__ Xin,
    float* __restrict__ Xout)
{
  extern __shared__ float sh[];
  float* S_ = sh;                   // [128][132]
  float* X_ = sh + 128 * 132;       // [128][133]
  float* W_ = X_ + 128 * 133;       // [128][33]
  const int tile = blockIdx.x;      // 0..3
  const int b    = blockIdx.y;
  const int j0   = tile * 32;
  const int tid  = threadIdx.x;
  const float* __restrict__ Sg = AAt + (size_t)b * NK * NK;
  const float* __restrict__ Xg = Xin + (size_t)b * NK * NK;
  float* __restrict__ Og       = Xout + (size_t)b * NK * NK;
  for (int idx = tid; idx < NK * NK; idx += 256) {
    int rr = idx >> 7, cc = idx & 127;
    S_[rr * 132 + cc] = Sg[idx];
    X_[rr * 133 + cc] = Xg[idx];
  }
  __syncthreads();

  const int kg  = tid >> 4;
  const int jj2 = (tid & 15) * 2;

  float aw[8][2];
#pragma unroll
  for (int u = 0; u < 8; u++) { aw[u][0] = 0.f; aw[u][1] = 0.f; }
  for (int m = 0; m < NK; m++) {
    const float x0 = X_[m * 133 + j0 + jj2];
    const float x1 = X_[m * 133 + j0 + jj2 + 1];
    float4 s0 = *(const float4*)&S_[m * 132 + kg * 8];
    float4 s1 = *(const float4*)&S_[m * 132 + kg * 8 + 4];
    const float sv[8] = {s0.x, s0.y, s0.z, s0.w, s1.x, s1.y, s1.z, s1.w};
#pragma unroll
    for (int u = 0; u < 8; u++) {
      aw[u][0] = fmaf(sv[u], x0, aw[u][0]);
      aw[u][1] = fmaf(sv[u], x1, aw[u][1]);
    }
  }
#pragma unroll
  for (int u = 0; u < 8; u++) {
#pragma unroll
    for (int j = 0; j < 2; j++) {
      const int k = kg * 8 + u;
      float val = -aw[u][j];
      if (k == j0 + jj2 + j) val += 2.f;
      W_[k * 33 + jj2 + j] = val;
    }
  }
  __syncthreads();

  float ax[8][2];
#pragma unroll
  for (int u = 0; u < 8; u++) { ax[u][0] = 0.f; ax[u][1] = 0.f; }
  for (int k = 0; k < NK; k++) {
    const float w0 = W_[k * 33 + jj2];
    const float w1 = W_[k * 33 + jj2 + 1];
#pragma unroll
    for (int u = 0; u < 8; u++) {
      const float x = X_[(kg * 8 + u) * 133 + k];
      ax[u][0] = fmaf(x, w0, ax[u][0]);
      ax[u][1] = fmaf(x, w1, ax[u][1]);
    }
  }
#pragma unroll
  for (int u = 0; u < 8; u++) {
    Og[(size_t)(kg * 8 + u) * NK + j0 + jj2]     = ax[u][0];
    Og[(size_t)(kg * 8 + u) * NK + j0 + jj2 + 1] = ax[u][1];
  }
}

// ---------------------------------------------------------------------------
// 5) Solve via Neumann fixed point, ROW-PARALLEL.
// ---------------------------------------------------------------------------
__global__ __launch_bounds__(256) void solve_kernel(
    const float* __restrict__ Sinv, const float* __restrict__ BAt,
    const float* __restrict__ Dm, float* __restrict__ Cxy)
{
  extern __shared__ float sh[];
  float* SinvS = sh;               // [128][132]
  float* ZS    = sh + 128 * 132;   // [32][133]
  const int tile = blockIdx.x;
  const int b    = blockIdx.y;
  const int i0b  = tile * 32;
  const int tid  = threadIdx.x;
  const float* __restrict__ Sb = Sinv + (size_t)b * NK * NK;
  const float* __restrict__ Rb = BAt  + (size_t)b * NK * NK;
  const float* __restrict__ Db = Dm   + (size_t)b * NK * NK;
  for (int idx = tid; idx < NK * NK; idx += 256) {
    SinvS[(idx >> 7) * 132 + (idx & 127)] = Sb[idx];
  }
  for (int idx = tid; idx < 32 * NK; idx += 256) {
    int rr = idx >> 7, cc = idx & 127;
    ZS[rr * 133 + cc] = Rb[(size_t)(i0b + rr) * NK + cc];
  }
  __syncthreads();

  const int il = (tid >> 4) * 2;
  const int r0 = (tid & 15) * 8;
  float Y[2][8], X[2][8];
#pragma unroll
  for (int u = 0; u < 2; u++)
#pragma unroll
    for (int v = 0; v < 8; v++) Y[u][v] = 0.f;

  for (int c = 0; c < NK; c++) {
    float4 s0 = *(const float4*)&SinvS[c * 132 + r0];
    float4 s1 = *(const float4*)&SinvS[c * 132 + r0 + 4];
#pragma unroll
    for (int u = 0; u < 2; u++) {
      float z = ZS[(il + u) * 133 + c];
      Y[u][0] = fmaf(z, s0.x, Y[u][0]);
      Y[u][1] = fmaf(z, s0.y, Y[u][1]);
      Y[u][2] = fmaf(z, s0.z, Y[u][2]);
      Y[u][3] = fmaf(z, s0.w, Y[u][3]);
      Y[u][4] = fmaf(z, s1.x, Y[u][4]);
      Y[u][5] = fmaf(z, s1.y, Y[u][5]);
      Y[u][6] = fmaf(z, s1.z, Y[u][6]);
      Y[u][7] = fmaf(z, s1.w, Y[u][7]);
    }
  }
#pragma unroll
  for (int u = 0; u < 2; u++)
#pragma unroll
    for (int v = 0; v < 8; v++) X[u][v] = Y[u][v];

  for (int it = 0; it < 2; it++) {
    __syncthreads();
#pragma unroll
    for (int u = 0; u < 2; u++) {
      const float* drow = Db + (size_t)(i0b + il + u) * NK + r0;
      float* zrow = ZS + (il + u) * 133 + r0;
#pragma unroll
      for (int v = 0; v < 8; v++) zrow[v] = LMBDA * drow[v] * X[u][v];
    }
    __syncthreads();
#pragma unroll
    for (int u = 0; u < 2; u++)
#pragma unroll
      for (int v = 0; v < 8; v++) X[u][v] = Y[u][v];
    for (int c = 0; c < NK; c++) {
      float4 s0 = *(const float4*)&SinvS[c * 132 + r0];
      float4 s1 = *(const float4*)&SinvS[c * 132 + r0 + 4];
#pragma unroll
      for (int u = 0; u < 2; u++) {
        float z = ZS[(il + u) * 133 + c];
        X[u][0] = fmaf(-z, s0.x, X[u][0]);
        X[u][1] = fmaf(-z, s0.y, X[u][1]);
        X[u][2] = fmaf(-z, s0.z, X[u][2]);
        X[u][3] = fmaf(-z, s0.w, X[u][3]);
        X[u][4] = fmaf(-z, s1.x, X[u][4]);
        X[u][5] = fmaf(-z, s1.y, X[u][5]);
        X[u][6] = fmaf(-z, s1.z, X[u][6]);
        X[u][7] = fmaf(-z, s1.w, X[u][7]);
      }
    }
  }
  float* __restrict__ Ob = Cxy + ((size_t)b * NK + i0b + il) * NK + r0;
#pragma unroll
  for (int u = 0; u < 2; u++) {
    float4 o0 = make_float4(X[u][0], X[u][1], X[u][2], X[u][3]);
    float4 o1 = make_float4(X[u][4], X[u][5], X[u][6], X[u][7]);
    *(float4*)(Ob + (size_t)u * NK)     = o0;
    *(float4*)(Ob + (size_t)u * NK + 4) = o1;
  }
}

} // anonymous namespace

extern "C" void kernel_launch(void* const* d_in, const int* in_sizes, int n_in,
                              void* d_out, int out_size, void* d_ws, size_t ws_size,
                              hipStream_t stream) {
  (void)in_sizes; (void)n_in; (void)out_size;
  const float* feat_x  = (const float*)d_in[0];
  const float* feat_y  = (const float*)d_in[1];
  const float* evals_x = (const float*)d_in[2];
  const float* evals_y = (const float*)d_in[3];
  const float* etx     = (const float*)d_in[4];
  const float* ety     = (const float*)d_in[5];
  float* out = (float*)d_out;
  float* ws  = (float*)d_ws;

  float* A    = ws;
  float* Bm   = ws + 262144;
  float* AAt  = ws + 524288;
  float* BAt  = ws + 655360;
  float* Dm   = ws + 786432;
  float* Sinv = ws + 917504;
  float* P    = ws + 1048576;
  float* Sinv2 = Bm;   // Bm region dead after gram_kernel

  const bool use_partial = ws_size >= (size_t)(1048576 + 8388608) * 4;

  constexpr int PROJ_LDS  = 2 * 8192 * 2;                        // 32768 B (B-only)
  constexpr int INV_LDS   = (128 * 132 + 8 * 132) * 4;           // 71808 B
  constexpr int NS_LDS    = (128 * 132 + 128 * 133 + 128 * 33) * 4;   // 152576 B
  constexpr int SOLVE_LDS = (128 * 132 + 32 * 133) * 4;          // 84608 B
  hipFuncSetAttribute((const void*)proj_mfma<0>,
                      hipFuncAttributeMaxDynamicSharedMemorySize, PROJ_LDS);
  hipFuncSetAttribute((const void*)proj_mfma<1>,
                      hipFuncAttributeMaxDynamicSharedMemorySize, PROJ_LDS);
  hipFuncSetAttribute((const void*)invert_kernel,
                      hipFuncAttributeMaxDynamicSharedMemorySize, INV_LDS);
  hipFuncSetAttribute((const void*)ns_kernel,
                      hipFuncAttributeMaxDynamicSharedMemorySize, NS_LDS);
  hipFuncSetAttribute((const void*)solve_kernel,
                      hipFuncAttributeMaxDynamicSharedMemorySize, SOLVE_LDS);

  if (use_partial) {
    proj_mfma<0><<<dim3(CHUNKS, 2, 16), 256, PROJ_LDS, stream>>>(etx, feat_x, ety, feat_y, A, Bm, P);
    reduce_kernel<<<dim3(512), 256, 0, stream>>>(P, ws);
  } else {
    hipMemsetAsync(A, 0, (size_t)524288 * sizeof(float), stream);
    proj_mfma<1><<<dim3(CHUNKS, 2, 16), 256, PROJ_LDS, stream>>>(etx, feat_x, ety, feat_y, A, Bm, P);
  }
  gram_kernel<<<dim3(16, 8), 256, 0, stream>>>(A, Bm, AAt, BAt);
  mask_kernel<<<dim3(8), 256, 0, stream>>>(evals_x, evals_y, Dm);
  invert_kernel<<<dim3(8), 512, INV_LDS, stream>>>(AAt, Sinv);
  ns_kernel<<<dim3(4, 8), 256, NS_LDS, stream>>>(AAt, Sinv, Sinv2);
  ns_kernel<<<dim3(4, 8), 256, NS_LDS, stream>>>(AAt, Sinv2, Sinv);
  solve_kernel<<<dim3(4, 8), 256, SOLVE_LDS, stream>>>(Sinv, BAt, Dm, out);
}

// Round 15
// 325.678 us; speedup vs baseline: 1.5528x; 1.5528x over previous
//
#include <hip/hip_runtime.h>
#include <hip/hip_bf16.h>

namespace {

constexpr int NB = 8;
constexpr int NV = 20000;
constexpr int NC = 256;
constexpr int NK = 128;
constexpr float LMBDA = 100.0f;
constexpr int KSTEP = 32;
constexpr int CHUNKS = 16;      // v-chunks; chunk 0 gets 40 steps, rest 39

typedef __attribute__((ext_vector_type(8))) short bf16x8;
typedef __attribute__((ext_vector_type(4))) float f32x4;

// HW packed conversion: low16 = bf16(a), high16 = bf16(c); RTNE.
__device__ __forceinline__ uint cvtpk(float a, float c) {
  uint r;
  asm("v_cvt_pk_bf16_f32 %0, %1, %2" : "=v"(r) : "v"(a), "v"(c));
  return r;
}

// ---------------------------------------------------------------------------
// 1) Spectral projection via split-bf16 MFMA (hi*hi + hi*lo + lo*hi).
//    REVERTED to the round-11-benched best (267 us total): 512 thr, 64x32
//    wave tiles, cvtpk staging, double-buffered LDS, ONE barrier per step.
//    (Round-14's direct-A-load variant spilled to scratch: WRITE_SIZE 32->340MB.)
// ---------------------------------------------------------------------------
template <int MODE>
__global__ __launch_bounds__(512, 4) void proj_mfma(
    const float* __restrict__ Ex, const float* __restrict__ Fx,
    const float* __restrict__ Ey, const float* __restrict__ Fy,
    float* __restrict__ A, float* __restrict__ Bm, float* __restrict__ P)
{
  extern __shared__ ushort smem[];         // 2 bufs x (AH 8192 + BH 8192) ushorts

  const int chunk = blockIdx.x;            // 0..15
  const int ct    = blockIdx.y;            // 0..1 (c half)
  const int bs    = blockIdx.z;            // b*2+side
  const int b     = bs >> 1;
  const int side  = bs & 1;
  const float* __restrict__ E = (side ? Ey : Ex) + (size_t)b * NK * NV;
  const float* __restrict__ F = (side ? Fy : Fx) + (size_t)b * NV * NC;
  float* __restrict__ Out = (side ? Bm : A) + (size_t)b * NK * NC;
  const int cb = ct * 128;

  const int start = chunk * 39 + (chunk > 0 ? 1 : 0);
  const int nsteps = 39 + (chunk == 0 ? 1 : 0);
  const int v0 = start * KSTEP;

  const int tid  = threadIdx.x;
  const int lane = tid & 63;
  const int w    = tid >> 6;
  const int wm   = w >> 2;       // 0..1 (64-row group)
  const int wn   = w & 3;        // 0..3 (32-col group)
  const int lrow = lane >> 4;    // 0..3
  const int lcol = lane & 15;

  const int ek  = tid >> 2;
  const int evg = tid & 3;
  const int ef  = ek >> 4;
  const int entE = (((ek & 15) + evg * 4) & 15) + evg * 16;
  const float* Erow = E + (size_t)ek * NV + v0 + evg * 8;

  const int fp  = tid & 15;
  const int fc0 = (tid >> 4) * 4;
  const int fcg = fc0 >> 4;
  const int fclow = fc0 & 15;
  const int fvg = fp >> 2;
  const int fsp = fp & 3;

  f32x4 acc[4][2];
#pragma unroll
  for (int fi = 0; fi < 4; fi++)
#pragma unroll
    for (int ni = 0; ni < 2; ni++) acc[fi][ni] = (f32x4)0.f;

  const int entA = (((lcol) + lrow * 4) & 15) + lrow * 16;

  auto loadE = [&](int t, float4& a0, float4& a1) {
    const float* p = Erow + t * KSTEP;
    a0 = *(const float4*)(p);
    a1 = *(const float4*)(p + 4);
  };
  auto loadF = [&](int t, float4& b0, float4& b1) {
    const float* p = F + (size_t)(v0 + t * KSTEP + 2 * fp) * NC + cb + fc0;
    b0 = *(const float4*)(p);
    b1 = *(const float4*)(p + NC);
  };

  auto stage = [&](int buf, float4 e0, float4 e1, float4 f0, float4 f1) {
    ushort* AHb = smem + buf * 16384;
    ushort* BHb = AHb + 8192;
    const float v[8] = {e0.x, e0.y, e0.z, e0.w, e1.x, e1.y, e1.z, e1.w};
    uint hiw[4], low[4];
#pragma unroll
    for (int i = 0; i < 4; i++) {
      float a = v[2 * i], c = v[2 * i + 1];
      uint h = cvtpk(a, c);
      low[i] = cvtpk(a - __uint_as_float(h << 16),
                     c - __uint_as_float(h & 0xffff0000u));
      hiw[i] = h;
    }
    *(uint4*)(AHb + ef * 512 + entE * 8)        = make_uint4(hiw[0], hiw[1], hiw[2], hiw[3]);
    *(uint4*)(AHb + 4096 + ef * 512 + entE * 8) = make_uint4(low[0], low[1], low[2], low[3]);

    const float* fa = (const float*)&f0;
    const float* fb = (const float*)&f1;
#pragma unroll
    for (int j = 0; j < 4; j++) {
      int ent = ((fclow + j + fcg) & 15) + fvg * 16;
      float a = fa[j], c = fb[j];
      uint h = cvtpk(a, c);
      uint l = cvtpk(a - __uint_as_float(h << 16),
                     c - __uint_as_float(h & 0xffff0000u));
      *(uint*)(BHb + fcg * 512 + ent * 8 + 2 * fsp) = h;
      *(uint*)(BHb + 4096 + fcg * 512 + ent * 8 + 2 * fsp) = l;
    }
  };

  auto domfma = [&](int buf) {
    const ushort* AHb = smem + buf * 16384;
    const ushort* BHb = AHb + 8192;
    bf16x8 bHf[2], bLf[2];
#pragma unroll
    for (int ni = 0; ni < 2; ni++) {
      int cg = wn * 2 + ni;
      int entB = ((lcol + cg) & 15) + lrow * 16;
      bHf[ni] = *(const bf16x8*)(BHb + cg * 512 + entB * 8);
      bLf[ni] = *(const bf16x8*)(BHb + 4096 + cg * 512 + entB * 8);
    }
#pragma unroll
    for (int fi = 0; fi < 4; fi++) {
      bf16x8 aH = *(const bf16x8*)(AHb + (wm * 4 + fi) * 512 + entA * 8);
      bf16x8 aL = *(const bf16x8*)(AHb + 4096 + (wm * 4 + fi) * 512 + entA * 8);
#pragma unroll
      for (int ni = 0; ni < 2; ni++) {
        acc[fi][ni] = __builtin_amdgcn_mfma_f32_16x16x32_bf16(aH, bHf[ni], acc[fi][ni], 0, 0, 0);
        acc[fi][ni] = __builtin_amdgcn_mfma_f32_16x16x32_bf16(aH, bLf[ni], acc[fi][ni], 0, 0, 0);
        acc[fi][ni] = __builtin_amdgcn_mfma_f32_16x16x32_bf16(aL, bHf[ni], acc[fi][ni], 0, 0, 0);
      }
    }
  };

  // ---- pipeline prologue ----
  float4 eA0, eA1, fA0, fA1, eB0, eB1, fB0, fB1;
  loadE(0, eA0, eA1); loadF(0, fA0, fA1);
  stage(0, eA0, eA1, fA0, fA1);
  {
    const int t1 = (1 < nsteps) ? 1 : 0;
    loadE(t1, eB0, eB1); loadF(t1, fB0, fB1);
  }
  __syncthreads();

  // ---- main loop: ONE barrier per step ----
  for (int s = 0; s < nsteps; s++) {
    const int bufc = s & 1;
    if (s + 1 < nsteps) {
      if ((s & 1) == 0) stage(bufc ^ 1, eB0, eB1, fB0, fB1);
      else              stage(bufc ^ 1, eA0, eA1, fA0, fA1);
    }
    if (s + 2 < nsteps) {
      if ((s & 1) == 0) { loadE(s + 2, eA0, eA1); loadF(s + 2, fA0, fA1); }
      else              { loadE(s + 2, eB0, eB1); loadF(s + 2, fB0, fB1); }
    }
    domfma(bufc);
    __syncthreads();
  }

  // ---- epilogue: C/D layout col=lane&15, row=(lane>>4)*4+reg ----
#pragma unroll
  for (int fi = 0; fi < 4; fi++) {
#pragma unroll
    for (int ni = 0; ni < 2; ni++) {
      const float* av = (const float*)&acc[fi][ni];
#pragma unroll
      for (int q = 0; q < 4; q++) {
        int row = wm * 64 + fi * 16 + lrow * 4 + q;
        int col = cb + wn * 32 + ni * 16 + lcol;
        if (MODE == 0) {
          P[(((size_t)chunk * 16 + bs) * NK + row) * NC + col] = av[q];
        } else {
          atomicAdd(&Out[(size_t)row * NC + col], av[q]);
        }
      }
    }
  }
}

__global__ __launch_bounds__(256) void reduce_kernel(
    const float* __restrict__ P, float* __restrict__ AB)
{
  const int g = blockIdx.x * 256 + threadIdx.x;
  const int bsi = g >> 13;
  const int rem4 = g & 8191;
  const int side = bsi & 1, b = bsi >> 1;
  float4 s = make_float4(0.f, 0.f, 0.f, 0.f);
#pragma unroll
  for (int ch = 0; ch < CHUNKS; ch++) {
    float4 v = *(const float4*)(P + (((size_t)ch * 16 + bsi) * 8192 + rem4) * 4);
    s.x += v.x; s.y += v.y; s.z += v.z; s.w += v.w;
  }
  *(float4*)(AB + ((size_t)side * 262144 + (size_t)b * 8192 * 4 + (size_t)rem4 * 4)) = s;
}

// ---------------------------------------------------------------------------
// 2) Gram
// ---------------------------------------------------------------------------
__global__ __launch_bounds__(256) void gram_kernel(
    const float* __restrict__ A, const float* __restrict__ Bm,
    float* __restrict__ AAt, float* __restrict__ BAt)
{
  const int i0 = blockIdx.x * 8;
  const int b  = blockIdx.y;
  __shared__ float Xi[16][260];
  const float* __restrict__ Ab = A  + (size_t)b * NK * NC;
  const float* __restrict__ Bb = Bm + (size_t)b * NK * NC;
  const int tid = threadIdx.x;
  for (int idx = tid; idx < 16 * 64; idx += 256) {
    int row = idx >> 6, c4 = idx & 63;
    const float* src = (row < 8) ? (Ab + (size_t)(i0 + row) * NC)
                                 : (Bb + (size_t)(i0 + row - 8) * NC);
    *(float4*)&Xi[row][c4 * 4] = *(const float4*)(src + c4 * 4);
  }
  __syncthreads();
  const int j = tid & 127;
  const int m = tid >> 7;
  const float* __restrict__ Arow = Ab + (size_t)j * NC;
  float accv[8];
#pragma unroll
  for (int i = 0; i < 8; i++) accv[i] = 0.f;
  for (int c4 = 0; c4 < 64; c4++) {
    float4 a4 = *(const float4*)(Arow + c4 * 4);
#pragma unroll
    for (int i = 0; i < 8; i++) {
      float4 x4 = *(const float4*)&Xi[m * 8 + i][c4 * 4];
      accv[i] = fmaf(x4.x, a4.x, accv[i]);
      accv[i] = fmaf(x4.y, a4.y, accv[i]);
      accv[i] = fmaf(x4.z, a4.z, accv[i]);
      accv[i] = fmaf(x4.w, a4.w, accv[i]);
    }
  }
  float* Outp = (m ? BAt : AAt) + ((size_t)b * NK + i0) * NK + j;
#pragma unroll
  for (int i = 0; i < 8; i++) Outp[(size_t)i * NK] = accv[i];
}

// ---------------------------------------------------------------------------
// 3) Mask D
// ---------------------------------------------------------------------------
__global__ __launch_bounds__(256) void mask_kernel(
    const float* __restrict__ evx, const float* __restrict__ evy,
    float* __restrict__ Dm)
{
  const int b = blockIdx.x;
  const int tid = threadIdx.x;
  __shared__ float red[256];
  __shared__ float t1x[128], t2x[128], t1y[128], t2y[128];
  float v = (tid < 128) ? evx[b * 128 + tid] : evy[b * 128 + (tid - 128)];
  red[tid] = v;
  __syncthreads();
  for (int sft = 128; sft > 0; sft >>= 1) {
    if (tid < sft) red[tid] = fmaxf(red[tid], red[tid + sft]);
    __syncthreads();
  }
  const float inv_scale = 1.0f / red[0];
  if (tid < 128) {
    float e = evx[b * 128 + tid] * inv_scale;
    float g = sqrtf(e);
    float d = 1.f / (g * g + 1.f);
    t1x[tid] = g * d;  t2x[tid] = d;
  } else {
    int i = tid - 128;
    float e = evy[b * 128 + i] * inv_scale;
    float g = sqrtf(e);
    float d = 1.f / (g * g + 1.f);
    t1y[i] = g * d;  t2y[i] = d;
  }
  __syncthreads();
  float* __restrict__ Db = Dm + (size_t)b * NK * NK;
  for (int idx = tid; idx < NK * NK; idx += 256) {
    int i = idx >> 7, jj = idx & 127;
    float re = t1y[i] - t1x[jj];
    float im = t2y[i] - t2x[jj];
    Db[idx] = re * re + im * im;
  }
}

// ---------------------------------------------------------------------------
// 4) FUSED: blocked Gauss-Jordan (W=8, verbatim-verified) + 2x Newton-Schulz.
//    LDS: M[128][132] | S2[128][132] | T[128][33] (T doubles as GJ's R).
//    S kept resident; NS accumulation order matches the old ns_kernel
//    exactly (AAt bit-symmetric) -> bit-identical Sinv.
// ---------------------------------------------------------------------------
__global__ __launch_bounds__(512) void invert_ns_kernel(
    const float* __restrict__ AAt, float* __restrict__ Gs,
    float* __restrict__ Sinv)
{
  extern __shared__ float sh[];
  float* M  = sh;                        // [128][132]
  float* S2 = sh + 128 * 132;            // [128][132]
  float* T  = sh + 2 * 128 * 132;        // [128][33]; GJ's R = [8][132] fits
  const int b = blockIdx.x;
  const int tid = threadIdx.x;
  const float* __restrict__ Sb = AAt + (size_t)b * NK * NK;
  for (int idx = tid; idx < NK * NK; idx += 512) {
    const float v = Sb[idx];
    M [(idx >> 7) * 132 + (idx & 127)] = v;
    S2[(idx >> 7) * 132 + (idx & 127)] = v;
  }
  __syncthreads();

  // ---- GJ, W=8 panels (verbatim from verified invert_kernel; R := T) ----
  {
    float* R = T;
    const int r = tid & 127;
    const int h = tid >> 7;
    const int c0 = h * 32;

    for (int p = 0; p < 16; p++) {
      const int J0 = p * 8;
      const bool inJ = (r >= J0) && (r < J0 + 8);
      const int i0 = r - J0;

      float g[8][8];
#pragma unroll
      for (int i = 0; i < 8; i++)
#pragma unroll
        for (int j = 0; j < 8; j++) g[i][j] = M[(J0 + i) * 132 + J0 + j];

#pragma unroll
      for (int j = 0; j < 8; j++) {
        const float invd = 1.f / g[j][j];
#pragma unroll
        for (int i = 0; i < 8; i++) {
          if (i == j) continue;
          const float f = g[i][j] * invd;
#pragma unroll
          for (int c = 0; c < 8; c++) {
            if (c == j) continue;
            g[i][c] = fmaf(-f, g[j][c], g[i][c]);
          }
          g[i][j] = -f;
        }
#pragma unroll
        for (int c = 0; c < 8; c++) {
          if (c == j) continue;
          g[j][c] *= invd;
        }
        g[j][j] = invd;
      }

      float c8[8];
      if (inJ) {
#pragma unroll
        for (int q = 0; q < 8; q++) {
          float v = 0.f;
#pragma unroll
          for (int i = 0; i < 8; i++)
            if (i0 == i) v = g[i][q];
          c8[q] = ((i0 == q) ? 1.f : 0.f) - v;
        }
      } else {
        float mr8[8];
#pragma unroll
        for (int k = 0; k < 8; k++) mr8[k] = M[r * 132 + J0 + k];
#pragma unroll
        for (int q = 0; q < 8; q++) {
          float a = 0.f;
#pragma unroll
          for (int k = 0; k < 8; k++) a = fmaf(mr8[k], g[k][q], a);
          c8[q] = a;
        }
      }

      if (inJ) {
#pragma unroll
        for (int i = 0; i < 8; i++)
          *(float4*)&R[i0 * 132 + c0 + i * 4] = *(const float4*)&M[r * 132 + c0 + i * 4];
      }
      __syncthreads();

      float4 m[8];
#pragma unroll
      for (int i = 0; i < 8; i++) m[i] = *(const float4*)&M[r * 132 + c0 + i * 4];
#pragma unroll
      for (int k = 0; k < 8; k++) {
        const float f = c8[k];
#pragma unroll
        for (int i = 0; i < 8; i++) {
          float4 rv = *(const float4*)&R[k * 132 + c0 + i * 4];
          m[i].x = fmaf(-f, rv.x, m[i].x);
          m[i].y = fmaf(-f, rv.y, m[i].y);
          m[i].z = fmaf(-f, rv.z, m[i].z);
          m[i].w = fmaf(-f, rv.w, m[i].w);
        }
      }
      {
        const bool panelH = (h == (J0 >> 5));
        const int q4 = (J0 & 31) >> 2;
        float sp[8];
#pragma unroll
        for (int q = 0; q < 8; q++)
          sp[q] = -c8[q] + ((inJ && i0 == q) ? 1.f : 0.f);
        const float4 lo = make_float4(sp[0], sp[1], sp[2], sp[3]);
        const float4 hi = make_float4(sp[4], sp[5], sp[6], sp[7]);
#pragma unroll
        for (int i = 0; i < 8; i++) {
          if (panelH && i == q4)     m[i] = lo;
          if (panelH && i == q4 + 1) m[i] = hi;
        }
      }
#pragma unroll
      for (int i = 0; i < 8; i++) *(float4*)&M[r * 132 + c0 + i * 4] = m[i];
      __syncthreads();
    }
  }

  // ---- 2x Newton-Schulz: X <- X(2I - S*X), tile-by-tile; M holds X ----
  float* __restrict__ Gb = Gs   + (size_t)b * NK * NK;
  float* __restrict__ Ob = Sinv + (size_t)b * NK * NK;
  const int kg4 = (tid >> 4) * 4;        // 4 rows (32 groups)
  const int jj2 = (tid & 15) * 2;        // 2 cols within 32-col tile

  for (int iter = 0; iter < 2; iter++) {
    float* __restrict__ Yg = (iter == 0) ? Gb : Ob;
#pragma unroll 1
    for (int jt = 0; jt < 4; jt++) {
      const int j0 = jt * 32;
      __syncthreads();                   // T free from previous use
      // W-tile: T[k][jj] = 2I - sum_m S2[k][m] * M[m][j0+jj]
      float aw[4][2];
#pragma unroll
      for (int u = 0; u < 4; u++) { aw[u][0] = 0.f; aw[u][1] = 0.f; }
      for (int m = 0; m < NK; m++) {
        const float x0 = M[m * 132 + j0 + jj2];
        const float x1 = M[m * 132 + j0 + jj2 + 1];
#pragma unroll
        for (int u = 0; u < 4; u++) {
          const float s = S2[(kg4 + u) * 132 + m];
          aw[u][0] = fmaf(s, x0, aw[u][0]);
          aw[u][1] = fmaf(s, x1, aw[u][1]);
        }
      }
#pragma unroll
      for (int u = 0; u < 4; u++) {
#pragma unroll
        for (int j = 0; j < 2; j++) {
          const int k = kg4 + u;
          float val = -aw[u][j];
          if (k == j0 + jj2 + j) val += 2.f;
          T[k * 33 + jj2 + j] = val;
        }
      }
      __syncthreads();
      // Y-tile: Yg[i][j0+jj] = sum_k M[i][k] * T[k][jj]
      float ay[4][2];
#pragma unroll
      for (int u = 0; u < 4; u++) { ay[u][0] = 0.f; ay[u][1] = 0.f; }
      for (int k = 0; k < NK; k++) {
        const float w0 = T[k * 33 + jj2];
        const float w1 = T[k * 33 + jj2 + 1];
#pragma unroll
        for (int u = 0; u < 4; u++) {
          const float x = M[(kg4 + u) * 132 + k];
          ay[u][0] = fmaf(x, w0, ay[u][0]);
          ay[u][1] = fmaf(x, w1, ay[u][1]);
        }
      }
#pragma unroll
      for (int u = 0; u < 4; u++) {
        Yg[(size_t)(kg4 + u) * NK + j0 + jj2]     = ay[u][0];
        Yg[(size_t)(kg4 + u) * NK + j0 + jj2 + 1] = ay[u][1];
      }
    }
    __syncthreads();                     // drains global writes (vmcnt) too
    if (iter == 0) {
      for (int idx = tid; idx < NK * NK; idx += 512)
        M[(idx >> 7) * 132 + (idx & 127)] = Gb[idx];
    }
  }
}

// ---------------------------------------------------------------------------
// 5) Solve via Neumann fixed point, ROW-PARALLEL.
// ---------------------------------------------------------------------------
__global__ __launch_bounds__(256) void solve_kernel(
    const float* __restrict__ Sinv, const float* __restrict__ BAt,
    const float* __restrict__ Dm, float* __restrict__ Cxy)
{
  extern __shared__ float sh[];
  float* SinvS = sh;               // [128][132]
  float* ZS    = sh + 128 * 132;   // [32][133]
  const int tile = blockIdx.x;
  const int b    = blockIdx.y;
  const int i0b  = tile * 32;
  const int tid  = threadIdx.x;
  const float* __restrict__ Sb = Sinv + (size_t)b * NK * NK;
  const float* __restrict__ Rb = BAt  + (size_t)b * NK * NK;
  const float* __restrict__ Db = Dm   + (size_t)b * NK * NK;
  for (int idx = tid; idx < NK * NK; idx += 256) {
    SinvS[(idx >> 7) * 132 + (idx & 127)] = Sb[idx];
  }
  for (int idx = tid; idx < 32 * NK; idx += 256) {
    int rr = idx >> 7, cc = idx & 127;
    ZS[rr * 133 + cc] = Rb[(size_t)(i0b + rr) * NK + cc];
  }
  __syncthreads();

  const int il = (tid >> 4) * 2;
  const int r0 = (tid & 15) * 8;
  float Y[2][8], X[2][8];
#pragma unroll
  for (int u = 0; u < 2; u++)
#pragma unroll
    for (int v = 0; v < 8; v++) Y[u][v] = 0.f;

  for (int c = 0; c < NK; c++) {
    float4 s0 = *(const float4*)&SinvS[c * 132 + r0];
    float4 s1 = *(const float4*)&SinvS[c * 132 + r0 + 4];
#pragma unroll
    for (int u = 0; u < 2; u++) {
      float z = ZS[(il + u) * 133 + c];
      Y[u][0] = fmaf(z, s0.x, Y[u][0]);
      Y[u][1] = fmaf(z, s0.y, Y[u][1]);
      Y[u][2] = fmaf(z, s0.z, Y[u][2]);
      Y[u][3] = fmaf(z, s0.w, Y[u][3]);
      Y[u][4] = fmaf(z, s1.x, Y[u][4]);
      Y[u][5] = fmaf(z, s1.y, Y[u][5]);
      Y[u][6] = fmaf(z, s1.z, Y[u][6]);
      Y[u][7] = fmaf(z, s1.w, Y[u][7]);
    }
  }
#pragma unroll
  for (int u = 0; u < 2; u++)
#pragma unroll
    for (int v = 0; v < 8; v++) X[u][v] = Y[u][v];

  for (int it = 0; it < 2; it++) {
    __syncthreads();
#pragma unroll
    for (int u = 0; u < 2; u++) {
      const float* drow = Db + (size_t)(i0b + il + u) * NK + r0;
      float* zrow = ZS + (il + u) * 133 + r0;
#pragma unroll
      for (int v = 0; v < 8; v++) zrow[v] = LMBDA * drow[v] * X[u][v];
    }
    __syncthreads();
#pragma unroll
    for (int u = 0; u < 2; u++)
#pragma unroll
      for (int v = 0; v < 8; v++) X[u][v] = Y[u][v];
    for (int c = 0; c < NK; c++) {
      float4 s0 = *(const float4*)&SinvS[c * 132 + r0];
      float4 s1 = *(const float4*)&SinvS[c * 132 + r0 + 4];
#pragma unroll
      for (int u = 0; u < 2; u++) {
        float z = ZS[(il + u) * 133 + c];
        X[u][0] = fmaf(-z, s0.x, X[u][0]);
        X[u][1] = fmaf(-z, s0.y, X[u][1]);
        X[u][2] = fmaf(-z, s0.z, X[u][2]);
        X[u][3] = fmaf(-z, s0.w, X[u][3]);
        X[u][4] = fmaf(-z, s1.x, X[u][4]);
        X[u][5] = fmaf(-z, s1.y, X[u][5]);
        X[u][6] = fmaf(-z, s1.z, X[u][6]);
        X[u][7] = fmaf(-z, s1.w, X[u][7]);
      }
    }
  }
  float* __restrict__ Ob = Cxy + ((size_t)b * NK + i0b + il) * NK + r0;
#pragma unroll
  for (int u = 0; u < 2; u++) {
    float4 o0 = make_float4(X[u][0], X[u][1], X[u][2], X[u][3]);
    float4 o1 = make_float4(X[u][4], X[u][5], X[u][6], X[u][7]);
    *(float4*)(Ob + (size_t)u * NK)     = o0;
    *(float4*)(Ob + (size_t)u * NK + 4) = o1;
  }
}

} // anonymous namespace

extern "C" void kernel_launch(void* const* d_in, const int* in_sizes, int n_in,
                              void* d_out, int out_size, void* d_ws, size_t ws_size,
                              hipStream_t stream) {
  (void)in_sizes; (void)n_in; (void)out_size;
  const float* feat_x  = (const float*)d_in[0];
  const float* feat_y  = (const float*)d_in[1];
  const float* evals_x = (const float*)d_in[2];
  const float* evals_y = (const float*)d_in[3];
  const float* etx     = (const float*)d_in[4];
  const float* ety     = (const float*)d_in[5];
  float* out = (float*)d_out;
  float* ws  = (float*)d_ws;

  float* A    = ws;
  float* Bm   = ws + 262144;
  float* AAt  = ws + 524288;
  float* BAt  = ws + 655360;
  float* Dm   = ws + 786432;
  float* Sinv = ws + 917504;
  float* P    = ws + 1048576;
  float* Gscr = Bm;   // Bm region dead after gram_kernel

  const bool use_partial = ws_size >= (size_t)(1048576 + 8388608) * 4;

  constexpr int PROJ_LDS   = 2 * 16384 * 2;                     // 65536 B
  constexpr int INVNS_LDS  = (2 * 128 * 132 + 128 * 33) * 4;    // 152064 B
  constexpr int SOLVE_LDS  = (128 * 132 + 32 * 133) * 4;        // 84608 B
  hipFuncSetAttribute((const void*)proj_mfma<0>,
                      hipFuncAttributeMaxDynamicSharedMemorySize, PROJ_LDS);
  hipFuncSetAttribute((const void*)proj_mfma<1>,
                      hipFuncAttributeMaxDynamicSharedMemorySize, PROJ_LDS);
  hipFuncSetAttribute((const void*)invert_ns_kernel,
                      hipFuncAttributeMaxDynamicSharedMemorySize, INVNS_LDS);
  hipFuncSetAttribute((const void*)solve_kernel,
                      hipFuncAttributeMaxDynamicSharedMemorySize, SOLVE_LDS);

  if (use_partial) {
    proj_mfma<0><<<dim3(CHUNKS, 2, 16), 512, PROJ_LDS, stream>>>(etx, feat_x, ety, feat_y, A, Bm, P);
    reduce_kernel<<<dim3(512), 256, 0, stream>>>(P, ws);
  } else {
    hipMemsetAsync(A, 0, (size_t)524288 * sizeof(float), stream);
    proj_mfma<1><<<dim3(CHUNKS, 2, 16), 512, PROJ_LDS, stream>>>(etx, feat_x, ety, feat_y, A, Bm, P);
  }
  gram_kernel<<<dim3(16, 8), 256, 0, stream>>>(A, Bm, AAt, BAt);
  mask_kernel<<<dim3(8), 256, 0, stream>>>(evals_x, evals_y, Dm);
  invert_ns_kernel<<<dim3(8), 512, INVNS_LDS, stream>>>(AAt, Gscr, Sinv);
  solve_kernel<<<dim3(4, 8), 256, SOLVE_LDS, stream>>>(Sinv, BAt, Dm, out);
}

// Round 16
// 324.247 us; speedup vs baseline: 1.5597x; 1.0044x over previous
//
#include <hip/hip_runtime.h>
#include <hip/hip_bf16.h>

namespace {

constexpr int NB = 8;
constexpr int NV = 20000;
constexpr int NC = 256;
constexpr int NK = 128;
constexpr float LMBDA = 100.0f;
constexpr int KSTEP = 32;
constexpr int CHUNKS = 16;      // v-chunks; chunk 0 gets 40 steps, rest 39

typedef __attribute__((ext_vector_type(8))) short bf16x8;
typedef __attribute__((ext_vector_type(4))) float f32x4;

// HW packed conversion: low16 = bf16(a), high16 = bf16(c); RTNE.
__device__ __forceinline__ uint cvtpk(float a, float c) {
  uint r;
  asm("v_cvt_pk_bf16_f32 %0, %1, %2" : "=v"(r) : "v"(a), "v"(c));
  return r;
}

// ---------------------------------------------------------------------------
// 1) Spectral projection via split-bf16 MFMA (hi*hi + hi*lo + lo*hi).
//    Round-11-benched best: 512 thr, 64x32 wave tiles, cvtpk staging,
//    double-buffered LDS, ONE barrier per step.
// ---------------------------------------------------------------------------
template <int MODE>
__global__ __launch_bounds__(512, 4) void proj_mfma(
    const float* __restrict__ Ex, const float* __restrict__ Fx,
    const float* __restrict__ Ey, const float* __restrict__ Fy,
    float* __restrict__ A, float* __restrict__ Bm, float* __restrict__ P)
{
  extern __shared__ ushort smem[];         // 2 bufs x (AH 8192 + BH 8192) ushorts

  const int chunk = blockIdx.x;            // 0..15
  const int ct    = blockIdx.y;            // 0..1 (c half)
  const int bs    = blockIdx.z;            // b*2+side
  const int b     = bs >> 1;
  const int side  = bs & 1;
  const float* __restrict__ E = (side ? Ey : Ex) + (size_t)b * NK * NV;
  const float* __restrict__ F = (side ? Fy : Fx) + (size_t)b * NV * NC;
  float* __restrict__ Out = (side ? Bm : A) + (size_t)b * NK * NC;
  const int cb = ct * 128;

  const int start = chunk * 39 + (chunk > 0 ? 1 : 0);
  const int nsteps = 39 + (chunk == 0 ? 1 : 0);
  const int v0 = start * KSTEP;

  const int tid  = threadIdx.x;
  const int lane = tid & 63;
  const int w    = tid >> 6;
  const int wm   = w >> 2;       // 0..1 (64-row group)
  const int wn   = w & 3;        // 0..3 (32-col group)
  const int lrow = lane >> 4;    // 0..3
  const int lcol = lane & 15;

  const int ek  = tid >> 2;
  const int evg = tid & 3;
  const int ef  = ek >> 4;
  const int entE = (((ek & 15) + evg * 4) & 15) + evg * 16;
  const float* Erow = E + (size_t)ek * NV + v0 + evg * 8;

  const int fp  = tid & 15;
  const int fc0 = (tid >> 4) * 4;
  const int fcg = fc0 >> 4;
  const int fclow = fc0 & 15;
  const int fvg = fp >> 2;
  const int fsp = fp & 3;

  f32x4 acc[4][2];
#pragma unroll
  for (int fi = 0; fi < 4; fi++)
#pragma unroll
    for (int ni = 0; ni < 2; ni++) acc[fi][ni] = (f32x4)0.f;

  const int entA = (((lcol) + lrow * 4) & 15) + lrow * 16;

  auto loadE = [&](int t, float4& a0, float4& a1) {
    const float* p = Erow + t * KSTEP;
    a0 = *(const float4*)(p);
    a1 = *(const float4*)(p + 4);
  };
  auto loadF = [&](int t, float4& b0, float4& b1) {
    const float* p = F + (size_t)(v0 + t * KSTEP + 2 * fp) * NC + cb + fc0;
    b0 = *(const float4*)(p);
    b1 = *(const float4*)(p + NC);
  };

  auto stage = [&](int buf, float4 e0, float4 e1, float4 f0, float4 f1) {
    ushort* AHb = smem + buf * 16384;
    ushort* BHb = AHb + 8192;
    const float v[8] = {e0.x, e0.y, e0.z, e0.w, e1.x, e1.y, e1.z, e1.w};
    uint hiw[4], low[4];
#pragma unroll
    for (int i = 0; i < 4; i++) {
      float a = v[2 * i], c = v[2 * i + 1];
      uint h = cvtpk(a, c);
      low[i] = cvtpk(a - __uint_as_float(h << 16),
                     c - __uint_as_float(h & 0xffff0000u));
      hiw[i] = h;
    }
    *(uint4*)(AHb + ef * 512 + entE * 8)        = make_uint4(hiw[0], hiw[1], hiw[2], hiw[3]);
    *(uint4*)(AHb + 4096 + ef * 512 + entE * 8) = make_uint4(low[0], low[1], low[2], low[3]);

    const float* fa = (const float*)&f0;
    const float* fb = (const float*)&f1;
#pragma unroll
    for (int j = 0; j < 4; j++) {
      int ent = ((fclow + j + fcg) & 15) + fvg * 16;
      float a = fa[j], c = fb[j];
      uint h = cvtpk(a, c);
      uint l = cvtpk(a - __uint_as_float(h << 16),
                     c - __uint_as_float(h & 0xffff0000u));
      *(uint*)(BHb + fcg * 512 + ent * 8 + 2 * fsp) = h;
      *(uint*)(BHb + 4096 + fcg * 512 + ent * 8 + 2 * fsp) = l;
    }
  };

  auto domfma = [&](int buf) {
    const ushort* AHb = smem + buf * 16384;
    const ushort* BHb = AHb + 8192;
    bf16x8 bHf[2], bLf[2];
#pragma unroll
    for (int ni = 0; ni < 2; ni++) {
      int cg = wn * 2 + ni;
      int entB = ((lcol + cg) & 15) + lrow * 16;
      bHf[ni] = *(const bf16x8*)(BHb + cg * 512 + entB * 8);
      bLf[ni] = *(const bf16x8*)(BHb + 4096 + cg * 512 + entB * 8);
    }
#pragma unroll
    for (int fi = 0; fi < 4; fi++) {
      bf16x8 aH = *(const bf16x8*)(AHb + (wm * 4 + fi) * 512 + entA * 8);
      bf16x8 aL = *(const bf16x8*)(AHb + 4096 + (wm * 4 + fi) * 512 + entA * 8);
#pragma unroll
      for (int ni = 0; ni < 2; ni++) {
        acc[fi][ni] = __builtin_amdgcn_mfma_f32_16x16x32_bf16(aH, bHf[ni], acc[fi][ni], 0, 0, 0);
        acc[fi][ni] = __builtin_amdgcn_mfma_f32_16x16x32_bf16(aH, bLf[ni], acc[fi][ni], 0, 0, 0);
        acc[fi][ni] = __builtin_amdgcn_mfma_f32_16x16x32_bf16(aL, bHf[ni], acc[fi][ni], 0, 0, 0);
      }
    }
  };

  // ---- pipeline prologue ----
  float4 eA0, eA1, fA0, fA1, eB0, eB1, fB0, fB1;
  loadE(0, eA0, eA1); loadF(0, fA0, fA1);
  stage(0, eA0, eA1, fA0, fA1);
  {
    const int t1 = (1 < nsteps) ? 1 : 0;
    loadE(t1, eB0, eB1); loadF(t1, fB0, fB1);
  }
  __syncthreads();

  // ---- main loop: ONE barrier per step ----
  for (int s = 0; s < nsteps; s++) {
    const int bufc = s & 1;
    if (s + 1 < nsteps) {
      if ((s & 1) == 0) stage(bufc ^ 1, eB0, eB1, fB0, fB1);
      else              stage(bufc ^ 1, eA0, eA1, fA0, fA1);
    }
    if (s + 2 < nsteps) {
      if ((s & 1) == 0) { loadE(s + 2, eA0, eA1); loadF(s + 2, fA0, fA1); }
      else              { loadE(s + 2, eB0, eB1); loadF(s + 2, fB0, fB1); }
    }
    domfma(bufc);
    __syncthreads();
  }

  // ---- epilogue: C/D layout col=lane&15, row=(lane>>4)*4+reg ----
#pragma unroll
  for (int fi = 0; fi < 4; fi++) {
#pragma unroll
    for (int ni = 0; ni < 2; ni++) {
      const float* av = (const float*)&acc[fi][ni];
#pragma unroll
      for (int q = 0; q < 4; q++) {
        int row = wm * 64 + fi * 16 + lrow * 4 + q;
        int col = cb + wn * 32 + ni * 16 + lcol;
        if (MODE == 0) {
          P[(((size_t)chunk * 16 + bs) * NK + row) * NC + col] = av[q];
        } else {
          atomicAdd(&Out[(size_t)row * NC + col], av[q]);
        }
      }
    }
  }
}

__global__ __launch_bounds__(256) void reduce_kernel(
    const float* __restrict__ P, float* __restrict__ AB)
{
  const int g = blockIdx.x * 256 + threadIdx.x;
  const int bsi = g >> 13;
  const int rem4 = g & 8191;
  const int side = bsi & 1, b = bsi >> 1;
  float4 s = make_float4(0.f, 0.f, 0.f, 0.f);
#pragma unroll
  for (int ch = 0; ch < CHUNKS; ch++) {
    float4 v = *(const float4*)(P + (((size_t)ch * 16 + bsi) * 8192 + rem4) * 4);
    s.x += v.x; s.y += v.y; s.z += v.z; s.w += v.w;
  }
  *(float4*)(AB + ((size_t)side * 262144 + (size_t)b * 8192 * 4 + (size_t)rem4 * 4)) = s;
}

// ---------------------------------------------------------------------------
// 2) Gram
// ---------------------------------------------------------------------------
__global__ __launch_bounds__(256) void gram_kernel(
    const float* __restrict__ A, const float* __restrict__ Bm,
    float* __restrict__ AAt, float* __restrict__ BAt)
{
  const int i0 = blockIdx.x * 8;
  const int b  = blockIdx.y;
  __shared__ float Xi[16][260];
  const float* __restrict__ Ab = A  + (size_t)b * NK * NC;
  const float* __restrict__ Bb = Bm + (size_t)b * NK * NC;
  const int tid = threadIdx.x;
  for (int idx = tid; idx < 16 * 64; idx += 256) {
    int row = idx >> 6, c4 = idx & 63;
    const float* src = (row < 8) ? (Ab + (size_t)(i0 + row) * NC)
                                 : (Bb + (size_t)(i0 + row - 8) * NC);
    *(float4*)&Xi[row][c4 * 4] = *(const float4*)(src + c4 * 4);
  }
  __syncthreads();
  const int j = tid & 127;
  const int m = tid >> 7;
  const float* __restrict__ Arow = Ab + (size_t)j * NC;
  float accv[8];
#pragma unroll
  for (int i = 0; i < 8; i++) accv[i] = 0.f;
  for (int c4 = 0; c4 < 64; c4++) {
    float4 a4 = *(const float4*)(Arow + c4 * 4);
#pragma unroll
    for (int i = 0; i < 8; i++) {
      float4 x4 = *(const float4*)&Xi[m * 8 + i][c4 * 4];
      accv[i] = fmaf(x4.x, a4.x, accv[i]);
      accv[i] = fmaf(x4.y, a4.y, accv[i]);
      accv[i] = fmaf(x4.z, a4.z, accv[i]);
      accv[i] = fmaf(x4.w, a4.w, accv[i]);
    }
  }
  float* Outp = (m ? BAt : AAt) + ((size_t)b * NK + i0) * NK + j;
#pragma unroll
  for (int i = 0; i < 8; i++) Outp[(size_t)i * NK] = accv[i];
}

// ---------------------------------------------------------------------------
// 3) Mask D
// ---------------------------------------------------------------------------
__global__ __launch_bounds__(256) void mask_kernel(
    const float* __restrict__ evx, const float* __restrict__ evy,
    float* __restrict__ Dm)
{
  const int b = blockIdx.x;
  const int tid = threadIdx.x;
  __shared__ float red[256];
  __shared__ float t1x[128], t2x[128], t1y[128], t2y[128];
  float v = (tid < 128) ? evx[b * 128 + tid] : evy[b * 128 + (tid - 128)];
  red[tid] = v;
  __syncthreads();
  for (int sft = 128; sft > 0; sft >>= 1) {
    if (tid < sft) red[tid] = fmaxf(red[tid], red[tid + sft]);
    __syncthreads();
  }
  const float inv_scale = 1.0f / red[0];
  if (tid < 128) {
    float e = evx[b * 128 + tid] * inv_scale;
    float g = sqrtf(e);
    float d = 1.f / (g * g + 1.f);
    t1x[tid] = g * d;  t2x[tid] = d;
  } else {
    int i = tid - 128;
    float e = evy[b * 128 + i] * inv_scale;
    float g = sqrtf(e);
    float d = 1.f / (g * g + 1.f);
    t1y[i] = g * d;  t2y[i] = d;
  }
  __syncthreads();
  float* __restrict__ Db = Dm + (size_t)b * NK * NK;
  for (int idx = tid; idx < NK * NK; idx += 256) {
    int i = idx >> 7, jj = idx & 127;
    float re = t1y[i] - t1x[jj];
    float im = t2y[i] - t2x[jj];
    Db[idx] = re * re + im * im;
  }
}

// ---------------------------------------------------------------------------
// 4) FUSED: blocked Gauss-Jordan (W=8) + 2x Newton-Schulz.
//    __launch_bounds__(512, 2): LDS (152 KB, dynamic -> invisible to the
//    occupancy heuristic) limits to 1 block/CU anyway; without the hint the
//    compiler targeted 8 waves/SIMD and capped VGPR at 64, spilling g[8][8]
//    (round-15: 193 us, VALUBusy 1.4%). Cap 256 keeps g in registers.
// ---------------------------------------------------------------------------
__global__ __launch_bounds__(512, 2) void invert_ns_kernel(
    const float* __restrict__ AAt, float* __restrict__ Gs,
    float* __restrict__ Sinv)
{
  extern __shared__ float sh[];
  float* M  = sh;                        // [128][132]
  float* S2 = sh + 128 * 132;            // [128][132]
  float* T  = sh + 2 * 128 * 132;        // [128][33]; GJ's R = [8][132] fits
  const int b = blockIdx.x;
  const int tid = threadIdx.x;
  const float* __restrict__ Sb = AAt + (size_t)b * NK * NK;
  for (int idx = tid; idx < NK * NK; idx += 512) {
    const float v = Sb[idx];
    M [(idx >> 7) * 132 + (idx & 127)] = v;
    S2[(idx >> 7) * 132 + (idx & 127)] = v;
  }
  __syncthreads();

  // ---- GJ, W=8 panels (verbatim-verified; R := T) ----
  {
    float* R = T;
    const int r = tid & 127;
    const int h = tid >> 7;
    const int c0 = h * 32;

    for (int p = 0; p < 16; p++) {
      const int J0 = p * 8;
      const bool inJ = (r >= J0) && (r < J0 + 8);
      const int i0 = r - J0;

      float g[8][8];
#pragma unroll
      for (int i = 0; i < 8; i++)
#pragma unroll
        for (int j = 0; j < 8; j++) g[i][j] = M[(J0 + i) * 132 + J0 + j];

#pragma unroll
      for (int j = 0; j < 8; j++) {
        const float invd = 1.f / g[j][j];
#pragma unroll
        for (int i = 0; i < 8; i++) {
          if (i == j) continue;
          const float f = g[i][j] * invd;
#pragma unroll
          for (int c = 0; c < 8; c++) {
            if (c == j) continue;
            g[i][c] = fmaf(-f, g[j][c], g[i][c]);
          }
          g[i][j] = -f;
        }
#pragma unroll
        for (int c = 0; c < 8; c++) {
          if (c == j) continue;
          g[j][c] *= invd;
        }
        g[j][j] = invd;
      }

      float c8[8];
      if (inJ) {
#pragma unroll
        for (int q = 0; q < 8; q++) {
          float v = 0.f;
#pragma unroll
          for (int i = 0; i < 8; i++)
            if (i0 == i) v = g[i][q];
          c8[q] = ((i0 == q) ? 1.f : 0.f) - v;
        }
      } else {
        float mr8[8];
#pragma unroll
        for (int k = 0; k < 8; k++) mr8[k] = M[r * 132 + J0 + k];
#pragma unroll
        for (int q = 0; q < 8; q++) {
          float a = 0.f;
#pragma unroll
          for (int k = 0; k < 8; k++) a = fmaf(mr8[k], g[k][q], a);
          c8[q] = a;
        }
      }

      if (inJ) {
#pragma unroll
        for (int i = 0; i < 8; i++)
          *(float4*)&R[i0 * 132 + c0 + i * 4] = *(const float4*)&M[r * 132 + c0 + i * 4];
      }
      __syncthreads();

      float4 m[8];
#pragma unroll
      for (int i = 0; i < 8; i++) m[i] = *(const float4*)&M[r * 132 + c0 + i * 4];
#pragma unroll
      for (int k = 0; k < 8; k++) {
        const float f = c8[k];
#pragma unroll
        for (int i = 0; i < 8; i++) {
          float4 rv = *(const float4*)&R[k * 132 + c0 + i * 4];
          m[i].x = fmaf(-f, rv.x, m[i].x);
          m[i].y = fmaf(-f, rv.y, m[i].y);
          m[i].z = fmaf(-f, rv.z, m[i].z);
          m[i].w = fmaf(-f, rv.w, m[i].w);
        }
      }
      {
        const bool panelH = (h == (J0 >> 5));
        const int q4 = (J0 & 31) >> 2;
        float sp[8];
#pragma unroll
        for (int q = 0; q < 8; q++)
          sp[q] = -c8[q] + ((inJ && i0 == q) ? 1.f : 0.f);
        const float4 lo = make_float4(sp[0], sp[1], sp[2], sp[3]);
        const float4 hi = make_float4(sp[4], sp[5], sp[6], sp[7]);
#pragma unroll
        for (int i = 0; i < 8; i++) {
          if (panelH && i == q4)     m[i] = lo;
          if (panelH && i == q4 + 1) m[i] = hi;
        }
      }
#pragma unroll
      for (int i = 0; i < 8; i++) *(float4*)&M[r * 132 + c0 + i * 4] = m[i];
      __syncthreads();
    }
  }

  // ---- 2x Newton-Schulz: X <- X(2I - S*X), tile-by-tile; M holds X ----
  float* __restrict__ Gb = Gs   + (size_t)b * NK * NK;
  float* __restrict__ Ob = Sinv + (size_t)b * NK * NK;
  const int kg4 = (tid >> 4) * 4;        // 4 rows (32 groups)
  const int jj2 = (tid & 15) * 2;        // 2 cols within 32-col tile

  for (int iter = 0; iter < 2; iter++) {
    float* __restrict__ Yg = (iter == 0) ? Gb : Ob;
#pragma unroll 1
    for (int jt = 0; jt < 4; jt++) {
      const int j0 = jt * 32;
      __syncthreads();                   // T free from previous use
      float aw[4][2];
#pragma unroll
      for (int u = 0; u < 4; u++) { aw[u][0] = 0.f; aw[u][1] = 0.f; }
      for (int m = 0; m < NK; m++) {
        const float x0 = M[m * 132 + j0 + jj2];
        const float x1 = M[m * 132 + j0 + jj2 + 1];
#pragma unroll
        for (int u = 0; u < 4; u++) {
          const float s = S2[(kg4 + u) * 132 + m];
          aw[u][0] = fmaf(s, x0, aw[u][0]);
          aw[u][1] = fmaf(s, x1, aw[u][1]);
        }
      }
#pragma unroll
      for (int u = 0; u < 4; u++) {
#pragma unroll
        for (int j = 0; j < 2; j++) {
          const int k = kg4 + u;
          float val = -aw[u][j];
          if (k == j0 + jj2 + j) val += 2.f;
          T[k * 33 + jj2 + j] = val;
        }
      }
      __syncthreads();
      float ay[4][2];
#pragma unroll
      for (int u = 0; u < 4; u++) { ay[u][0] = 0.f; ay[u][1] = 0.f; }
      for (int k = 0; k < NK; k++) {
        const float w0 = T[k * 33 + jj2];
        const float w1 = T[k * 33 + jj2 + 1];
#pragma unroll
        for (int u = 0; u < 4; u++) {
          const float x = M[(kg4 + u) * 132 + k];
          ay[u][0] = fmaf(x, w0, ay[u][0]);
          ay[u][1] = fmaf(x, w1, ay[u][1]);
        }
      }
#pragma unroll
      for (int u = 0; u < 4; u++) {
        Yg[(size_t)(kg4 + u) * NK + j0 + jj2]     = ay[u][0];
        Yg[(size_t)(kg4 + u) * NK + j0 + jj2 + 1] = ay[u][1];
      }
    }
    __syncthreads();
    if (iter == 0) {
      for (int idx = tid; idx < NK * NK; idx += 512)
        M[(idx >> 7) * 132 + (idx & 127)] = Gb[idx];
    }
  }
}

// ---------------------------------------------------------------------------
// 5) Solve via Neumann fixed point, ROW-PARALLEL.
// ---------------------------------------------------------------------------
__global__ __launch_bounds__(256) void solve_kernel(
    const float* __restrict__ Sinv, const float* __restrict__ BAt,
    const float* __restrict__ Dm, float* __restrict__ Cxy)
{
  extern __shared__ float sh[];
  float* SinvS = sh;               // [128][132]
  float* ZS    = sh + 128 * 132;   // [32][133]
  const int tile = blockIdx.x;
  const int b    = blockIdx.y;
  const int i0b  = tile * 32;
  const int tid  = threadIdx.x;
  const float* __restrict__ Sb = Sinv + (size_t)b * NK * NK;
  const float* __restrict__ Rb = BAt  + (size_t)b * NK * NK;
  const float* __restrict__ Db = Dm   + (size_t)b * NK * NK;
  for (int idx = tid; idx < NK * NK; idx += 256) {
    SinvS[(idx >> 7) * 132 + (idx & 127)] = Sb[idx];
  }
  for (int idx = tid; idx < 32 * NK; idx += 256) {
    int rr = idx >> 7, cc = idx & 127;
    ZS[rr * 133 + cc] = Rb[(size_t)(i0b + rr) * NK + cc];
  }
  __syncthreads();

  const int il = (tid >> 4) * 2;
  const int r0 = (tid & 15) * 8;
  float Y[2][8], X[2][8];
#pragma unroll
  for (int u = 0; u < 2; u++)
#pragma unroll
    for (int v = 0; v < 8; v++) Y[u][v] = 0.f;

  for (int c = 0; c < NK; c++) {
    float4 s0 = *(const float4*)&SinvS[c * 132 + r0];
    float4 s1 = *(const float4*)&SinvS[c * 132 + r0 + 4];
#pragma unroll
    for (int u = 0; u < 2; u++) {
      float z = ZS[(il + u) * 133 + c];
      Y[u][0] = fmaf(z, s0.x, Y[u][0]);
      Y[u][1] = fmaf(z, s0.y, Y[u][1]);
      Y[u][2] = fmaf(z, s0.z, Y[u][2]);
      Y[u][3] = fmaf(z, s0.w, Y[u][3]);
      Y[u][4] = fmaf(z, s1.x, Y[u][4]);
      Y[u][5] = fmaf(z, s1.y, Y[u][5]);
      Y[u][6] = fmaf(z, s1.z, Y[u][6]);
      Y[u][7] = fmaf(z, s1.w, Y[u][7]);
    }
  }
#pragma unroll
  for (int u = 0; u < 2; u++)
#pragma unroll
    for (int v = 0; v < 8; v++) X[u][v] = Y[u][v];

  for (int it = 0; it < 2; it++) {
    __syncthreads();
#pragma unroll
    for (int u = 0; u < 2; u++) {
      const float* drow = Db + (size_t)(i0b + il + u) * NK + r0;
      float* zrow = ZS + (il + u) * 133 + r0;
#pragma unroll
      for (int v = 0; v < 8; v++) zrow[v] = LMBDA * drow[v] * X[u][v];
    }
    __syncthreads();
#pragma unroll
    for (int u = 0; u < 2; u++)
#pragma unroll
      for (int v = 0; v < 8; v++) X[u][v] = Y[u][v];
    for (int c = 0; c < NK; c++) {
      float4 s0 = *(const float4*)&SinvS[c * 132 + r0];
      float4 s1 = *(const float4*)&SinvS[c * 132 + r0 + 4];
#pragma unroll
      for (int u = 0; u < 2; u++) {
        float z = ZS[(il + u) * 133 + c];
        X[u][0] = fmaf(-z, s0.x, X[u][0]);
        X[u][1] = fmaf(-z, s0.y, X[u][1]);
        X[u][2] = fmaf(-z, s0.z, X[u][2]);
        X[u][3] = fmaf(-z, s0.w, X[u][3]);
        X[u][4] = fmaf(-z, s1.x, X[u][4]);
        X[u][5] = fmaf(-z, s1.y, X[u][5]);
        X[u][6] = fmaf(-z, s1.z, X[u][6]);
        X[u][7] = fmaf(-z, s1.w, X[u][7]);
      }
    }
  }
  float* __restrict__ Ob = Cxy + ((size_t)b * NK + i0b + il) * NK + r0;
#pragma unroll
  for (int u = 0; u < 2; u++) {
    float4 o0 = make_float4(X[u][0], X[u][1], X[u][2], X[u][3]);
    float4 o1 = make_float4(X[u][4], X[u][5], X[u][6], X[u][7]);
    *(float4*)(Ob + (size_t)u * NK)     = o0;
    *(float4*)(Ob + (size_t)u * NK + 4) = o1;
  }
}

} // anonymous namespace

extern "C" void kernel_launch(void* const* d_in, const int* in_sizes, int n_in,
                              void* d_out, int out_size, void* d_ws, size_t ws_size,
                              hipStream_t stream) {
  (void)in_sizes; (void)n_in; (void)out_size;
  const float* feat_x  = (const float*)d_in[0];
  const float* feat_y  = (const float*)d_in[1];
  const float* evals_x = (const float*)d_in[2];
  const float* evals_y = (const float*)d_in[3];
  const float* etx     = (const float*)d_in[4];
  const float* ety     = (const float*)d_in[5];
  float* out = (float*)d_out;
  float* ws  = (float*)d_ws;

  float* A    = ws;
  float* Bm   = ws + 262144;
  float* AAt  = ws + 524288;
  float* BAt  = ws + 655360;
  float* Dm   = ws + 786432;
  float* Sinv = ws + 917504;
  float* P    = ws + 1048576;
  float* Gscr = Bm;   // Bm region dead after gram_kernel

  const bool use_partial = ws_size >= (size_t)(1048576 + 8388608) * 4;

  constexpr int PROJ_LDS   = 2 * 16384 * 2;                     // 65536 B
  constexpr int INVNS_LDS  = (2 * 128 * 132 + 128 * 33) * 4;    // 152064 B
  constexpr int SOLVE_LDS  = (128 * 132 + 32 * 133) * 4;        // 84608 B
  hipFuncSetAttribute((const void*)proj_mfma<0>,
                      hipFuncAttributeMaxDynamicSharedMemorySize, PROJ_LDS);
  hipFuncSetAttribute((const void*)proj_mfma<1>,
                      hipFuncAttributeMaxDynamicSharedMemorySize, PROJ_LDS);
  hipFuncSetAttribute((const void*)invert_ns_kernel,
                      hipFuncAttributeMaxDynamicSharedMemorySize, INVNS_LDS);
  hipFuncSetAttribute((const void*)solve_kernel,
                      hipFuncAttributeMaxDynamicSharedMemorySize, SOLVE_LDS);

  if (use_partial) {
    proj_mfma<0><<<dim3(CHUNKS, 2, 16), 512, PROJ_LDS, stream>>>(etx, feat_x, ety, feat_y, A, Bm, P);
    reduce_kernel<<<dim3(512), 256, 0, stream>>>(P, ws);
  } else {
    hipMemsetAsync(A, 0, (size_t)524288 * sizeof(float), stream);
    proj_mfma<1><<<dim3(CHUNKS, 2, 16), 512, PROJ_LDS, stream>>>(etx, feat_x, ety, feat_y, A, Bm, P);
  }
  gram_kernel<<<dim3(16, 8), 256, 0, stream>>>(A, Bm, AAt, BAt);
  mask_kernel<<<dim3(8), 256, 0, stream>>>(evals_x, evals_y, Dm);
  invert_ns_kernel<<<dim3(8), 512, INVNS_LDS, stream>>>(AAt, Gscr, Sinv);
  solve_kernel<<<dim3(4, 8), 256, SOLVE_LDS, stream>>>(Sinv, BAt, Dm, out);
}

// Round 17
// 266.984 us; speedup vs baseline: 1.8942x; 1.2145x over previous
//
#include <hip/hip_runtime.h>
#include <hip/hip_bf16.h>

namespace {

constexpr int NB = 8;
constexpr int NV = 20000;
constexpr int NC = 256;
constexpr int NK = 128;
constexpr float LMBDA = 100.0f;
constexpr int KSTEP = 32;
constexpr int CHUNKS = 16;      // v-chunks; chunk 0 gets 40 steps, rest 39

typedef __attribute__((ext_vector_type(8))) short bf16x8;
typedef __attribute__((ext_vector_type(4))) float f32x4;

// HW packed conversion: low16 = bf16(a), high16 = bf16(c); RTNE.
__device__ __forceinline__ uint cvtpk(float a, float c) {
  uint r;
  asm("v_cvt_pk_bf16_f32 %0, %1, %2" : "=v"(r) : "v"(a), "v"(c));
  return r;
}

// ---------------------------------------------------------------------------
// 1) Spectral projection via split-bf16 MFMA (hi*hi + hi*lo + lo*hi).
//    Best-benched config (round-11, 267 us total): 512 thr, 64x32 wave
//    tiles, cvtpk staging, double-buffered LDS, ONE barrier per step.
// ---------------------------------------------------------------------------
template <int MODE>
__global__ __launch_bounds__(512, 4) void proj_mfma(
    const float* __restrict__ Ex, const float* __restrict__ Fx,
    const float* __restrict__ Ey, const float* __restrict__ Fy,
    float* __restrict__ A, float* __restrict__ Bm, float* __restrict__ P)
{
  extern __shared__ ushort smem[];         // 2 bufs x (AH 8192 + BH 8192) ushorts

  const int chunk = blockIdx.x;            // 0..15
  const int ct    = blockIdx.y;            // 0..1 (c half)
  const int bs    = blockIdx.z;            // b*2+side
  const int b     = bs >> 1;
  const int side  = bs & 1;
  const float* __restrict__ E = (side ? Ey : Ex) + (size_t)b * NK * NV;
  const float* __restrict__ F = (side ? Fy : Fx) + (size_t)b * NV * NC;
  float* __restrict__ Out = (side ? Bm : A) + (size_t)b * NK * NC;
  const int cb = ct * 128;

  const int start = chunk * 39 + (chunk > 0 ? 1 : 0);
  const int nsteps = 39 + (chunk == 0 ? 1 : 0);
  const int v0 = start * KSTEP;

  const int tid  = threadIdx.x;
  const int lane = tid & 63;
  const int w    = tid >> 6;
  const int wm   = w >> 2;       // 0..1 (64-row group)
  const int wn   = w & 3;        // 0..3 (32-col group)
  const int lrow = lane >> 4;    // 0..3
  const int lcol = lane & 15;

  const int ek  = tid >> 2;
  const int evg = tid & 3;
  const int ef  = ek >> 4;
  const int entE = (((ek & 15) + evg * 4) & 15) + evg * 16;
  const float* Erow = E + (size_t)ek * NV + v0 + evg * 8;

  const int fp  = tid & 15;
  const int fc0 = (tid >> 4) * 4;
  const int fcg = fc0 >> 4;
  const int fclow = fc0 & 15;
  const int fvg = fp >> 2;
  const int fsp = fp & 3;

  f32x4 acc[4][2];
#pragma unroll
  for (int fi = 0; fi < 4; fi++)
#pragma unroll
    for (int ni = 0; ni < 2; ni++) acc[fi][ni] = (f32x4)0.f;

  const int entA = (((lcol) + lrow * 4) & 15) + lrow * 16;

  auto loadE = [&](int t, float4& a0, float4& a1) {
    const float* p = Erow + t * KSTEP;
    a0 = *(const float4*)(p);
    a1 = *(const float4*)(p + 4);
  };
  auto loadF = [&](int t, float4& b0, float4& b1) {
    const float* p = F + (size_t)(v0 + t * KSTEP + 2 * fp) * NC + cb + fc0;
    b0 = *(const float4*)(p);
    b1 = *(const float4*)(p + NC);
  };

  auto stage = [&](int buf, float4 e0, float4 e1, float4 f0, float4 f1) {
    ushort* AHb = smem + buf * 16384;
    ushort* BHb = AHb + 8192;
    const float v[8] = {e0.x, e0.y, e0.z, e0.w, e1.x, e1.y, e1.z, e1.w};
    uint hiw[4], low[4];
#pragma unroll
    for (int i = 0; i < 4; i++) {
      float a = v[2 * i], c = v[2 * i + 1];
      uint h = cvtpk(a, c);
      low[i] = cvtpk(a - __uint_as_float(h << 16),
                     c - __uint_as_float(h & 0xffff0000u));
      hiw[i] = h;
    }
    *(uint4*)(AHb + ef * 512 + entE * 8)        = make_uint4(hiw[0], hiw[1], hiw[2], hiw[3]);
    *(uint4*)(AHb + 4096 + ef * 512 + entE * 8) = make_uint4(low[0], low[1], low[2], low[3]);

    const float* fa = (const float*)&f0;
    const float* fb = (const float*)&f1;
#pragma unroll
    for (int j = 0; j < 4; j++) {
      int ent = ((fclow + j + fcg) & 15) + fvg * 16;
      float a = fa[j], c = fb[j];
      uint h = cvtpk(a, c);
      uint l = cvtpk(a - __uint_as_float(h << 16),
                     c - __uint_as_float(h & 0xffff0000u));
      *(uint*)(BHb + fcg * 512 + ent * 8 + 2 * fsp) = h;
      *(uint*)(BHb + 4096 + fcg * 512 + ent * 8 + 2 * fsp) = l;
    }
  };

  auto domfma = [&](int buf) {
    const ushort* AHb = smem + buf * 16384;
    const ushort* BHb = AHb + 8192;
    bf16x8 bHf[2], bLf[2];
#pragma unroll
    for (int ni = 0; ni < 2; ni++) {
      int cg = wn * 2 + ni;
      int entB = ((lcol + cg) & 15) + lrow * 16;
      bHf[ni] = *(const bf16x8*)(BHb + cg * 512 + entB * 8);
      bLf[ni] = *(const bf16x8*)(BHb + 4096 + cg * 512 + entB * 8);
    }
#pragma unroll
    for (int fi = 0; fi < 4; fi++) {
      bf16x8 aH = *(const bf16x8*)(AHb + (wm * 4 + fi) * 512 + entA * 8);
      bf16x8 aL = *(const bf16x8*)(AHb + 4096 + (wm * 4 + fi) * 512 + entA * 8);
#pragma unroll
      for (int ni = 0; ni < 2; ni++) {
        acc[fi][ni] = __builtin_amdgcn_mfma_f32_16x16x32_bf16(aH, bHf[ni], acc[fi][ni], 0, 0, 0);
        acc[fi][ni] = __builtin_amdgcn_mfma_f32_16x16x32_bf16(aH, bLf[ni], acc[fi][ni], 0, 0, 0);
        acc[fi][ni] = __builtin_amdgcn_mfma_f32_16x16x32_bf16(aL, bHf[ni], acc[fi][ni], 0, 0, 0);
      }
    }
  };

  // ---- pipeline prologue ----
  float4 eA0, eA1, fA0, fA1, eB0, eB1, fB0, fB1;
  loadE(0, eA0, eA1); loadF(0, fA0, fA1);
  stage(0, eA0, eA1, fA0, fA1);
  {
    const int t1 = (1 < nsteps) ? 1 : 0;
    loadE(t1, eB0, eB1); loadF(t1, fB0, fB1);
  }
  __syncthreads();

  // ---- main loop: ONE barrier per step ----
  for (int s = 0; s < nsteps; s++) {
    const int bufc = s & 1;
    if (s + 1 < nsteps) {
      if ((s & 1) == 0) stage(bufc ^ 1, eB0, eB1, fB0, fB1);
      else              stage(bufc ^ 1, eA0, eA1, fA0, fA1);
    }
    if (s + 2 < nsteps) {
      if ((s & 1) == 0) { loadE(s + 2, eA0, eA1); loadF(s + 2, fA0, fA1); }
      else              { loadE(s + 2, eB0, eB1); loadF(s + 2, fB0, fB1); }
    }
    domfma(bufc);
    __syncthreads();
  }

  // ---- epilogue: C/D layout col=lane&15, row=(lane>>4)*4+reg ----
#pragma unroll
  for (int fi = 0; fi < 4; fi++) {
#pragma unroll
    for (int ni = 0; ni < 2; ni++) {
      const float* av = (const float*)&acc[fi][ni];
#pragma unroll
      for (int q = 0; q < 4; q++) {
        int row = wm * 64 + fi * 16 + lrow * 4 + q;
        int col = cb + wn * 32 + ni * 16 + lcol;
        if (MODE == 0) {
          P[(((size_t)chunk * 16 + bs) * NK + row) * NC + col] = av[q];
        } else {
          atomicAdd(&Out[(size_t)row * NC + col], av[q]);
        }
      }
    }
  }
}

__global__ __launch_bounds__(256) void reduce_kernel(
    const float* __restrict__ P, float* __restrict__ AB)
{
  const int g = blockIdx.x * 256 + threadIdx.x;
  const int bsi = g >> 13;
  const int rem4 = g & 8191;
  const int side = bsi & 1, b = bsi >> 1;
  float4 s = make_float4(0.f, 0.f, 0.f, 0.f);
#pragma unroll
  for (int ch = 0; ch < CHUNKS; ch++) {
    float4 v = *(const float4*)(P + (((size_t)ch * 16 + bsi) * 8192 + rem4) * 4);
    s.x += v.x; s.y += v.y; s.z += v.z; s.w += v.w;
  }
  *(float4*)(AB + ((size_t)side * 262144 + (size_t)b * 8192 * 4 + (size_t)rem4 * 4)) = s;
}

// ---------------------------------------------------------------------------
// 2) Gram
// ---------------------------------------------------------------------------
__global__ __launch_bounds__(256) void gram_kernel(
    const float* __restrict__ A, const float* __restrict__ Bm,
    float* __restrict__ AAt, float* __restrict__ BAt)
{
  const int i0 = blockIdx.x * 8;
  const int b  = blockIdx.y;
  __shared__ float Xi[16][260];
  const float* __restrict__ Ab = A  + (size_t)b * NK * NC;
  const float* __restrict__ Bb = Bm + (size_t)b * NK * NC;
  const int tid = threadIdx.x;
  for (int idx = tid; idx < 16 * 64; idx += 256) {
    int row = idx >> 6, c4 = idx & 63;
    const float* src = (row < 8) ? (Ab + (size_t)(i0 + row) * NC)
                                 : (Bb + (size_t)(i0 + row - 8) * NC);
    *(float4*)&Xi[row][c4 * 4] = *(const float4*)(src + c4 * 4);
  }
  __syncthreads();
  const int j = tid & 127;
  const int m = tid >> 7;
  const float* __restrict__ Arow = Ab + (size_t)j * NC;
  float accv[8];
#pragma unroll
  for (int i = 0; i < 8; i++) accv[i] = 0.f;
  for (int c4 = 0; c4 < 64; c4++) {
    float4 a4 = *(const float4*)(Arow + c4 * 4);
#pragma unroll
    for (int i = 0; i < 8; i++) {
      float4 x4 = *(const float4*)&Xi[m * 8 + i][c4 * 4];
      accv[i] = fmaf(x4.x, a4.x, accv[i]);
      accv[i] = fmaf(x4.y, a4.y, accv[i]);
      accv[i] = fmaf(x4.z, a4.z, accv[i]);
      accv[i] = fmaf(x4.w, a4.w, accv[i]);
    }
  }
  float* Outp = (m ? BAt : AAt) + ((size_t)b * NK + i0) * NK + j;
#pragma unroll
  for (int i = 0; i < 8; i++) Outp[(size_t)i * NK] = accv[i];
}

// ---------------------------------------------------------------------------
// 3) Mask D
// ---------------------------------------------------------------------------
__global__ __launch_bounds__(256) void mask_kernel(
    const float* __restrict__ evx, const float* __restrict__ evy,
    float* __restrict__ Dm)
{
  const int b = blockIdx.x;
  const int tid = threadIdx.x;
  __shared__ float red[256];
  __shared__ float t1x[128], t2x[128], t1y[128], t2y[128];
  float v = (tid < 128) ? evx[b * 128 + tid] : evy[b * 128 + (tid - 128)];
  red[tid] = v;
  __syncthreads();
  for (int sft = 128; sft > 0; sft >>= 1) {
    if (tid < sft) red[tid] = fmaxf(red[tid], red[tid + sft]);
    __syncthreads();
  }
  const float inv_scale = 1.0f / red[0];
  if (tid < 128) {
    float e = evx[b * 128 + tid] * inv_scale;
    float g = sqrtf(e);
    float d = 1.f / (g * g + 1.f);
    t1x[tid] = g * d;  t2x[tid] = d;
  } else {
    int i = tid - 128;
    float e = evy[b * 128 + i] * inv_scale;
    float g = sqrtf(e);
    float d = 1.f / (g * g + 1.f);
    t1y[i] = g * d;  t2y[i] = d;
  }
  __syncthreads();
  float* __restrict__ Db = Dm + (size_t)b * NK * NK;
  for (int idx = tid; idx < NK * NK; idx += 256) {
    int i = idx >> 7, jj = idx & 127;
    float re = t1y[i] - t1x[jj];
    float im = t2y[i] - t2x[jj];
    Db[idx] = re * re + im * im;
  }
}

// ---------------------------------------------------------------------------
// 4) Blocked Gauss-Jordan inversion, W=8 panels (round-8-verified).
// ---------------------------------------------------------------------------
__global__ __launch_bounds__(512) void invert_kernel(
    const float* __restrict__ AAt, float* __restrict__ Sinv)
{
  extern __shared__ float sh[];
  float* M = sh;                       // [128][132]
  float* R = sh + 128 * 132;           // [8][132] pivot-row snapshot
  const int b = blockIdx.x;
  const int tid = threadIdx.x;
  const float* __restrict__ Sb = AAt + (size_t)b * NK * NK;
  for (int idx = tid; idx < NK * NK; idx += 512) {
    M[(idx >> 7) * 132 + (idx & 127)] = Sb[idx];
  }
  __syncthreads();
  const int r = tid & 127;
  const int h = tid >> 7;
  const int c0 = h * 32;

  for (int p = 0; p < 16; p++) {
    const int J0 = p * 8;
    const bool inJ = (r >= J0) && (r < J0 + 8);
    const int i0 = r - J0;

    float g[8][8];
#pragma unroll
    for (int i = 0; i < 8; i++)
#pragma unroll
      for (int j = 0; j < 8; j++) g[i][j] = M[(J0 + i) * 132 + J0 + j];

#pragma unroll
    for (int j = 0; j < 8; j++) {
      const float invd = 1.f / g[j][j];
#pragma unroll
      for (int i = 0; i < 8; i++) {
        if (i == j) continue;
        const float f = g[i][j] * invd;
#pragma unroll
        for (int c = 0; c < 8; c++) {
          if (c == j) continue;
          g[i][c] = fmaf(-f, g[j][c], g[i][c]);
        }
        g[i][j] = -f;
      }
#pragma unroll
      for (int c = 0; c < 8; c++) {
        if (c == j) continue;
        g[j][c] *= invd;
      }
      g[j][j] = invd;
    }

    float c8[8];
    if (inJ) {
#pragma unroll
      for (int q = 0; q < 8; q++) {
        float v = 0.f;
#pragma unroll
        for (int i = 0; i < 8; i++)
          if (i0 == i) v = g[i][q];
        c8[q] = ((i0 == q) ? 1.f : 0.f) - v;
      }
    } else {
      float mr8[8];
#pragma unroll
      for (int k = 0; k < 8; k++) mr8[k] = M[r * 132 + J0 + k];
#pragma unroll
      for (int q = 0; q < 8; q++) {
        float a = 0.f;
#pragma unroll
        for (int k = 0; k < 8; k++) a = fmaf(mr8[k], g[k][q], a);
        c8[q] = a;
      }
    }

    if (inJ) {
#pragma unroll
      for (int i = 0; i < 8; i++)
        *(float4*)&R[i0 * 132 + c0 + i * 4] = *(const float4*)&M[r * 132 + c0 + i * 4];
    }
    __syncthreads();

    float4 m[8];
#pragma unroll
    for (int i = 0; i < 8; i++) m[i] = *(const float4*)&M[r * 132 + c0 + i * 4];
#pragma unroll
    for (int k = 0; k < 8; k++) {
      const float f = c8[k];
#pragma unroll
      for (int i = 0; i < 8; i++) {
        float4 rv = *(const float4*)&R[k * 132 + c0 + i * 4];
        m[i].x = fmaf(-f, rv.x, m[i].x);
        m[i].y = fmaf(-f, rv.y, m[i].y);
        m[i].z = fmaf(-f, rv.z, m[i].z);
        m[i].w = fmaf(-f, rv.w, m[i].w);
      }
    }
    {
      const bool panelH = (h == (J0 >> 5));
      const int q4 = (J0 & 31) >> 2;
      float sp[8];
#pragma unroll
      for (int q = 0; q < 8; q++)
        sp[q] = -c8[q] + ((inJ && i0 == q) ? 1.f : 0.f);
      const float4 lo = make_float4(sp[0], sp[1], sp[2], sp[3]);
      const float4 hi = make_float4(sp[4], sp[5], sp[6], sp[7]);
#pragma unroll
      for (int i = 0; i < 8; i++) {
        if (panelH && i == q4)     m[i] = lo;
        if (panelH && i == q4 + 1) m[i] = hi;
      }
    }
#pragma unroll
    for (int i = 0; i < 8; i++) *(float4*)&M[r * 132 + c0 + i * 4] = m[i];
    __syncthreads();
  }

  float* __restrict__ Ob = Sinv + (size_t)b * NK * NK;
  for (int idx = tid; idx < NK * NK; idx += 512) {
    Ob[idx] = M[(idx >> 7) * 132 + (idx & 127)];
  }
}

// ---------------------------------------------------------------------------
// 4b) Newton-Schulz, COLUMN-PARALLEL, 32 blocks (load-bearing; round-9 A/B).
// ---------------------------------------------------------------------------
__global__ __launch_bounds__(256) void ns_kernel(
    const float* __restrict__ AAt, const float* __restrict__ Xin,
    float* __restrict__ Xout)
{
  extern __shared__ float sh[];
  float* S_ = sh;                   // [128][132]
  float* X_ = sh + 128 * 132;       // [128][133]
  float* W_ = X_ + 128 * 133;       // [128][33]
  const int tile = blockIdx.x;      // 0..3
  const int b    = blockIdx.y;
  const int j0   = tile * 32;
  const int tid  = threadIdx.x;
  const float* __restrict__ Sg = AAt + (size_t)b * NK * NK;
  const float* __restrict__ Xg = Xin + (size_t)b * NK * NK;
  float* __restrict__ Og       = Xout + (size_t)b * NK * NK;
  for (int idx = tid; idx < NK * NK; idx += 256) {
    int rr = idx >> 7, cc = idx & 127;
    S_[rr * 132 + cc] = Sg[idx];
    X_[rr * 133 + cc] = Xg[idx];
  }
  __syncthreads();

  const int kg  = tid >> 4;
  const int jj2 = (tid & 15) * 2;

  float aw[8][2];
#pragma unroll
  for (int u = 0; u < 8; u++) { aw[u][0] = 0.f; aw[u][1] = 0.f; }
  for (int m = 0; m < NK; m++) {
    const float x0 = X_[m * 133 + j0 + jj2];
    const float x1 = X_[m * 133 + j0 + jj2 + 1];
    float4 s0 = *(const float4*)&S_[m * 132 + kg * 8];
    float4 s1 = *(const float4*)&S_[m * 132 + kg * 8 + 4];
    const float sv[8] = {s0.x, s0.y, s0.z, s0.w, s1.x, s1.y, s1.z, s1.w};
#pragma unroll
    for (int u = 0; u < 8; u++) {
      aw[u][0] = fmaf(sv[u], x0, aw[u][0]);
      aw[u][1] = fmaf(sv[u], x1, aw[u][1]);
    }
  }
#pragma unroll
  for (int u = 0; u < 8; u++) {
#pragma unroll
    for (int j = 0; j < 2; j++) {
      const int k = kg * 8 + u;
      float val = -aw[u][j];
      if (k == j0 + jj2 + j) val += 2.f;
      W_[k * 33 + jj2 + j] = val;
    }
  }
  __syncthreads();

  float ax[8][2];
#pragma unroll
  for (int u = 0; u < 8; u++) { ax[u][0] = 0.f; ax[u][1] = 0.f; }
  for (int k = 0; k < NK; k++) {
    const float w0 = W_[k * 33 + jj2];
    const float w1 = W_[k * 33 + jj2 + 1];
#pragma unroll
    for (int u = 0; u < 8; u++) {
      const float x = X_[(kg * 8 + u) * 133 + k];
      ax[u][0] = fmaf(x, w0, ax[u][0]);
      ax[u][1] = fmaf(x, w1, ax[u][1]);
    }
  }
#pragma unroll
  for (int u = 0; u < 8; u++) {
    Og[(size_t)(kg * 8 + u) * NK + j0 + jj2]     = ax[u][0];
    Og[(size_t)(kg * 8 + u) * NK + j0 + jj2 + 1] = ax[u][1];
  }
}

// ---------------------------------------------------------------------------
// 5) Solve via Neumann fixed point, ROW-PARALLEL, 32 blocks.
// ---------------------------------------------------------------------------
__global__ __launch_bounds__(256) void solve_kernel(
    const float* __restrict__ Sinv, const float* __restrict__ BAt,
    const float* __restrict__ Dm, float* __restrict__ Cxy)
{
  extern __shared__ float sh[];
  float* SinvS = sh;               // [128][132]
  float* ZS    = sh + 128 * 132;   // [32][133]
  const int tile = blockIdx.x;
  const int b    = blockIdx.y;
  const int i0b  = tile * 32;
  const int tid  = threadIdx.x;
  const float* __restrict__ Sb = Sinv + (size_t)b * NK * NK;
  const float* __restrict__ Rb = BAt  + (size_t)b * NK * NK;
  const float* __restrict__ Db = Dm   + (size_t)b * NK * NK;
  for (int idx = tid; idx < NK * NK; idx += 256) {
    SinvS[(idx >> 7) * 132 + (idx & 127)] = Sb[idx];
  }
  for (int idx = tid; idx < 32 * NK; idx += 256) {
    int rr = idx >> 7, cc = idx & 127;
    ZS[rr * 133 + cc] = Rb[(size_t)(i0b + rr) * NK + cc];
  }
  __syncthreads();

  const int il = (tid >> 4) * 2;
  const int r0 = (tid & 15) * 8;
  float Y[2][8], X[2][8];
#pragma unroll
  for (int u = 0; u < 2; u++)
#pragma unroll
    for (int v = 0; v < 8; v++) Y[u][v] = 0.f;

  for (int c = 0; c < NK; c++) {
    float4 s0 = *(const float4*)&SinvS[c * 132 + r0];
    float4 s1 = *(const float4*)&SinvS[c * 132 + r0 + 4];
#pragma unroll
    for (int u = 0; u < 2; u++) {
      float z = ZS[(il + u) * 133 + c];
      Y[u][0] = fmaf(z, s0.x, Y[u][0]);
      Y[u][1] = fmaf(z, s0.y, Y[u][1]);
      Y[u][2] = fmaf(z, s0.z, Y[u][2]);
      Y[u][3] = fmaf(z, s0.w, Y[u][3]);
      Y[u][4] = fmaf(z, s1.x, Y[u][4]);
      Y[u][5] = fmaf(z, s1.y, Y[u][5]);
      Y[u][6] = fmaf(z, s1.z, Y[u][6]);
      Y[u][7] = fmaf(z, s1.w, Y[u][7]);
    }
  }
#pragma unroll
  for (int u = 0; u < 2; u++)
#pragma unroll
    for (int v = 0; v < 8; v++) X[u][v] = Y[u][v];

  for (int it = 0; it < 2; it++) {
    __syncthreads();
#pragma unroll
    for (int u = 0; u < 2; u++) {
      const float* drow = Db + (size_t)(i0b + il + u) * NK + r0;
      float* zrow = ZS + (il + u) * 133 + r0;
#pragma unroll
      for (int v = 0; v < 8; v++) zrow[v] = LMBDA * drow[v] * X[u][v];
    }
    __syncthreads();
#pragma unroll
    for (int u = 0; u < 2; u++)
#pragma unroll
      for (int v = 0; v < 8; v++) X[u][v] = Y[u][v];
    for (int c = 0; c < NK; c++) {
      float4 s0 = *(const float4*)&SinvS[c * 132 + r0];
      float4 s1 = *(const float4*)&SinvS[c * 132 + r0 + 4];
#pragma unroll
      for (int u = 0; u < 2; u++) {
        float z = ZS[(il + u) * 133 + c];
        X[u][0] = fmaf(-z, s0.x, X[u][0]);
        X[u][1] = fmaf(-z, s0.y, X[u][1]);
        X[u][2] = fmaf(-z, s0.z, X[u][2]);
        X[u][3] = fmaf(-z, s0.w, X[u][3]);
        X[u][4] = fmaf(-z, s1.x, X[u][4]);
        X[u][5] = fmaf(-z, s1.y, X[u][5]);
        X[u][6] = fmaf(-z, s1.z, X[u][6]);
        X[u][7] = fmaf(-z, s1.w, X[u][7]);
      }
    }
  }
  float* __restrict__ Ob = Cxy + ((size_t)b * NK + i0b + il) * NK + r0;
#pragma unroll
  for (int u = 0; u < 2; u++) {
    float4 o0 = make_float4(X[u][0], X[u][1], X[u][2], X[u][3]);
    float4 o1 = make_float4(X[u][4], X[u][5], X[u][6], X[u][7]);
    *(float4*)(Ob + (size_t)u * NK)     = o0;
    *(float4*)(Ob + (size_t)u * NK + 4) = o1;
  }
}

} // anonymous namespace

extern "C" void kernel_launch(void* const* d_in, const int* in_sizes, int n_in,
                              void* d_out, int out_size, void* d_ws, size_t ws_size,
                              hipStream_t stream) {
  (void)in_sizes; (void)n_in; (void)out_size;
  const float* feat_x  = (const float*)d_in[0];
  const float* feat_y  = (const float*)d_in[1];
  const float* evals_x = (const float*)d_in[2];
  const float* evals_y = (const float*)d_in[3];
  const float* etx     = (const float*)d_in[4];
  const float* ety     = (const float*)d_in[5];
  float* out = (float*)d_out;
  float* ws  = (float*)d_ws;

  float* A    = ws;
  float* Bm   = ws + 262144;
  float* AAt  = ws + 524288;
  float* BAt  = ws + 655360;
  float* Dm   = ws + 786432;
  float* Sinv = ws + 917504;
  float* P    = ws + 1048576;
  float* Sinv2 = Bm;   // Bm region dead after gram_kernel

  const bool use_partial = ws_size >= (size_t)(1048576 + 8388608) * 4;

  constexpr int PROJ_LDS  = 2 * 16384 * 2;                       // 65536 B
  constexpr int INV_LDS   = (128 * 132 + 8 * 132) * 4;           // 71808 B
  constexpr int NS_LDS    = (128 * 132 + 128 * 133 + 128 * 33) * 4;   // 152576 B
  constexpr int SOLVE_LDS = (128 * 132 + 32 * 133) * 4;          // 84608 B
  hipFuncSetAttribute((const void*)proj_mfma<0>,
                      hipFuncAttributeMaxDynamicSharedMemorySize, PROJ_LDS);
  hipFuncSetAttribute((const void*)proj_mfma<1>,
                      hipFuncAttributeMaxDynamicSharedMemorySize, PROJ_LDS);
  hipFuncSetAttribute((const void*)invert_kernel,
                      hipFuncAttributeMaxDynamicSharedMemorySize, INV_LDS);
  hipFuncSetAttribute((const void*)ns_kernel,
                      hipFuncAttributeMaxDynamicSharedMemorySize, NS_LDS);
  hipFuncSetAttribute((const void*)solve_kernel,
                      hipFuncAttributeMaxDynamicSharedMemorySize, SOLVE_LDS);

  if (use_partial) {
    proj_mfma<0><<<dim3(CHUNKS, 2, 16), 512, PROJ_LDS, stream>>>(etx, feat_x, ety, feat_y, A, Bm, P);
    reduce_kernel<<<dim3(512), 256, 0, stream>>>(P, ws);
  } else {
    hipMemsetAsync(A, 0, (size_t)524288 * sizeof(float), stream);
    proj_mfma<1><<<dim3(CHUNKS, 2, 16), 512, PROJ_LDS, stream>>>(etx, feat_x, ety, feat_y, A, Bm, P);
  }
  gram_kernel<<<dim3(16, 8), 256, 0, stream>>>(A, Bm, AAt, BAt);
  mask_kernel<<<dim3(8), 256, 0, stream>>>(evals_x, evals_y, Dm);
  invert_kernel<<<dim3(8), 512, INV_LDS, stream>>>(AAt, Sinv);
  ns_kernel<<<dim3(4, 8), 256, NS_LDS, stream>>>(AAt, Sinv, Sinv2);
  ns_kernel<<<dim3(4, 8), 256, NS_LDS, stream>>>(AAt, Sinv2, Sinv);
  solve_kernel<<<dim3(4, 8), 256, SOLVE_LDS, stream>>>(Sinv, BAt, Dm, out);
}